// Round 1
// baseline (1096.244 us; speedup 1.0000x reference)
//
#include <hip/hip_runtime.h>

#define T_ 4
#define FI_ 128
#define FO_ 64
#define KD 512     // T*FI
#define OD 256     // T*FO

#define BM 64
#define BN 64
#define BK 64

static __device__ __forceinline__ float bf2f(unsigned short u){
  return __uint_as_float(((unsigned int)u) << 16);
}
static __device__ __forceinline__ unsigned short f2bf(float f){
  unsigned int u = __float_as_uint(f);
  u += 0x7FFFu + ((u >> 16) & 1u);
  return (unsigned short)(u >> 16);
}

// ---- degree histogram ----
__global__ __launch_bounds__(256) void k_degrees(const int* __restrict__ src,
    const int* __restrict__ dst, int* __restrict__ outdeg, int* __restrict__ indeg, int e)
{
  int i = blockIdx.x*256 + threadIdx.x;
  if (i < e){
    atomicAdd(&outdeg[src[i]], 1);
    atomicAdd(&indeg[dst[i]], 1);
  }
}

// ---- combined weight: Wc[(s*FI+f)][(t*FO+o)] = softmax(st_param)[t][s] * weight[t][f][o] ----
__global__ __launch_bounds__(256) void k_wc(const float* __restrict__ st_param,
    const float* __restrict__ weight, float* __restrict__ wc)
{
  int idx = blockIdx.x*256 + threadIdx.x;   // 512*256 total, exact grid
  int r = idx >> 8, c = idx & 255;
  int s = r >> 7, f = r & 127, t = c >> 6, o = c & 63;
  float p0 = st_param[t*4+0], p1 = st_param[t*4+1], p2 = st_param[t*4+2], p3 = st_param[t*4+3];
  float m = fmaxf(fmaxf(p0,p1), fmaxf(p2,p3));
  float e0 = expf(p0-m), e1 = expf(p1-m), e2 = expf(p2-m), e3 = expf(p3-m);
  float sum = e0+e1+e2+e3;
  float sel = (s==0)?e0:((s==1)?e1:((s==2)?e2:e3));
  wc[idx] = (sel/sum) * weight[(t*FI_+f)*FO_ + o];
}

// ---- norm_src = clip(outdeg,1)^-0.5 ----
__global__ __launch_bounds__(256) void k_norm(const int* __restrict__ outdeg,
    float* __restrict__ norm_src, int n)
{
  int i = blockIdx.x*256 + threadIdx.x;
  if (i < n){
    int d = outdeg[i]; if (d < 1) d = 1;
    norm_src[i] = rsqrtf((float)d);
  }
}

// ---- fp32 GEMM: h2[n][256] = (feat[n]*norm_src[n]) @ Wc, stored bf16 ----
__global__ __launch_bounds__(256) void k_gemm(const float* __restrict__ feat,
    const float* __restrict__ wc, const float* __restrict__ norm_src,
    unsigned short* __restrict__ h2, int n)
{
  __shared__ float As[BM][BK+4];
  __shared__ float Bs[BK][BN];
  const int row0 = blockIdx.x*BM, col0 = blockIdx.y*BN;
  const int t = threadIdx.x;
  const int tm = t >> 4, tn = t & 15;     // 16x16 threads, 4x4 each
  const int lr = t >> 4, lc = t & 15;     // loader layout
  float acc[4][4] = {};
  for (int k0 = 0; k0 < KD; k0 += BK){
    #pragma unroll
    for (int i = 0; i < 4; i++){
      int r = row0 + lr + 16*i;
      float4 v = {0.f, 0.f, 0.f, 0.f};
      if (r < n){
        v = *(const float4*)(feat + (size_t)r*KD + k0 + lc*4);
        float ns = norm_src[r];
        v.x *= ns; v.y *= ns; v.z *= ns; v.w *= ns;
      }
      *(float4*)(&As[lr + 16*i][lc*4]) = v;
    }
    #pragma unroll
    for (int i = 0; i < 4; i++){
      int kk = k0 + lr + 16*i;
      float4 v = *(const float4*)(wc + (size_t)kk*OD + col0 + lc*4);
      *(float4*)(&Bs[lr + 16*i][lc*4]) = v;
    }
    __syncthreads();
    #pragma unroll 8
    for (int k = 0; k < BK; k++){
      float4 b = *(const float4*)(&Bs[k][tn*4]);
      float a0 = As[tm*4+0][k];
      float a1 = As[tm*4+1][k];
      float a2 = As[tm*4+2][k];
      float a3 = As[tm*4+3][k];
      acc[0][0] += a0*b.x; acc[0][1] += a0*b.y; acc[0][2] += a0*b.z; acc[0][3] += a0*b.w;
      acc[1][0] += a1*b.x; acc[1][1] += a1*b.y; acc[1][2] += a1*b.z; acc[1][3] += a1*b.w;
      acc[2][0] += a2*b.x; acc[2][1] += a2*b.y; acc[2][2] += a2*b.z; acc[2][3] += a2*b.w;
      acc[3][0] += a3*b.x; acc[3][1] += a3*b.y; acc[3][2] += a3*b.z; acc[3][3] += a3*b.w;
    }
    __syncthreads();
  }
  #pragma unroll
  for (int i = 0; i < 4; i++){
    int r = row0 + tm*4 + i;
    if (r < n){
      ushort4 o4;
      o4.x = f2bf(acc[i][0]); o4.y = f2bf(acc[i][1]);
      o4.z = f2bf(acc[i][2]); o4.w = f2bf(acc[i][3]);
      *(ushort4*)(h2 + (size_t)r*OD + col0 + tn*4) = o4;
    }
  }
}

// ---- scan kernels: exclusive prefix over indeg -> CSR offsets ----
__global__ __launch_bounds__(256) void k_scan1(const int* __restrict__ cnt,
    int* __restrict__ bsum, int n)
{
  __shared__ int wsums[4];
  int b = blockIdx.x, t = threadIdx.x;
  int base = b*1024 + t*4;
  int s = 0;
  #pragma unroll
  for (int i = 0; i < 4; i++){ int idx = base+i; if (idx < n) s += cnt[idx]; }
  #pragma unroll
  for (int d = 1; d < 64; d <<= 1) s += __shfl_xor(s, d);
  if ((t & 63) == 0) wsums[t>>6] = s;
  __syncthreads();
  if (t == 0) bsum[b] = wsums[0]+wsums[1]+wsums[2]+wsums[3];
}

__global__ void k_scan2(const int* __restrict__ bsum, int* __restrict__ boff,
                        int nb, int* __restrict__ offsets, int n)
{
  int lane = threadIdx.x;  // 64 threads, 1 block
  int running = 0;
  for (int base = 0; base < nb; base += 64){
    int v = (base+lane < nb) ? bsum[base+lane] : 0;
    int x = v;
    #pragma unroll
    for (int d = 1; d < 64; d <<= 1){ int y = __shfl_up(x, d); if (lane >= d) x += y; }
    if (base+lane < nb) boff[base+lane] = running + x - v;
    running += __shfl(x, 63);
  }
  if (lane == 0) offsets[n] = running;   // = E
}

__global__ __launch_bounds__(256) void k_scan3(const int* __restrict__ cnt,
    const int* __restrict__ boff, int* __restrict__ offsets, int n)
{
  __shared__ int wsum[4], woff[4];
  int b = blockIdx.x, t = threadIdx.x, lane = t & 63, w = t >> 6;
  int base = b*1024 + t*4;
  int c[4]; int s = 0;
  #pragma unroll
  for (int i = 0; i < 4; i++){ c[i] = (base+i < n) ? cnt[base+i] : 0; s += c[i]; }
  int x = s;
  #pragma unroll
  for (int d = 1; d < 64; d <<= 1){ int y = __shfl_up(x, d); if (lane >= d) x += y; }
  if (lane == 63) wsum[w] = x;
  __syncthreads();
  if (t == 0){ int r = 0; for (int j = 0; j < 4; j++){ woff[j] = r; r += wsum[j]; } }
  __syncthreads();
  int excl = boff[b] + woff[w] + (x - s);
  #pragma unroll
  for (int i = 0; i < 4; i++){
    if (base+i < n) offsets[base+i] = excl;
    excl += c[i];
  }
}

// ---- counting-sort scatter: edges grouped by dst ----
__global__ __launch_bounds__(256) void k_scatter(const int* __restrict__ src,
    const int* __restrict__ dst, const int* __restrict__ offsets,
    int* __restrict__ cursor, int* __restrict__ esrc, int e)
{
  int i = blockIdx.x*256 + threadIdx.x;
  if (i < e){
    int d = dst[i];
    int pos = offsets[d] + atomicAdd(&cursor[d], 1);
    esrc[pos] = src[i];
  }
}

// ---- aggregation: one wave per dst node, register accumulation (no atomics) ----
__global__ __launch_bounds__(256) void k_agg(const unsigned short* __restrict__ h2,
    const int* __restrict__ offsets, const int* __restrict__ esrc,
    const int* __restrict__ indeg, const float* __restrict__ bias,
    float* __restrict__ out, int n)
{
  int node = (blockIdx.x*256 + threadIdx.x) >> 6;
  int lane = threadIdx.x & 63;
  if (node >= n) return;
  int beg = offsets[node], end = offsets[node+1];
  float ax = 0.f, ay = 0.f, az = 0.f, aw = 0.f;
  for (int i = beg; i < end; ++i){
    int s = esrc[i];
    ushort4 v = *(const ushort4*)(h2 + (size_t)s*OD + lane*4);
    ax += bf2f(v.x); ay += bf2f(v.y); az += bf2f(v.z); aw += bf2f(v.w);
  }
  int d = indeg[node]; if (d < 1) d = 1;
  float nd = rsqrtf((float)d);
  float4 bz = *(const float4*)(bias + lane*4);
  float4 o;
  o.x = ax*nd + bz.x; o.y = ay*nd + bz.y;
  o.z = az*nd + bz.z; o.w = aw*nd + bz.w;
  *(float4*)(out + (size_t)node*OD + lane*4) = o;
}

extern "C" void kernel_launch(void* const* d_in, const int* in_sizes, int n_in,
                              void* d_out, int out_size, void* d_ws, size_t ws_size,
                              hipStream_t stream)
{
  const float* feat     = (const float*)d_in[0];
  const float* weight   = (const float*)d_in[1];
  const float* bias     = (const float*)d_in[2];
  const float* st_param = (const float*)d_in[3];
  const int*   src      = (const int*)d_in[4];
  const int*   dst      = (const int*)d_in[5];
  const int N = in_sizes[0] / KD;
  const int E = in_sizes[4];

  char* w = (char*)d_ws;
  size_t off = 0;
  auto take = [&](size_t bytes) -> char* {
    char* p = w + off;
    off = (off + bytes + 255) & ~(size_t)255;
    return p;
  };
  int* outdeg   = (int*)take((size_t)N*4);
  int* indeg    = (int*)take((size_t)N*4);
  int* cursor   = (int*)take((size_t)N*4);
  char* zero_end = w + off;
  int* offsets  = (int*)take((size_t)(N+1)*4);
  int* bsum     = (int*)take(512*4);
  int* boff     = (int*)take(512*4);
  float* norm_src = (float*)take((size_t)N*4);
  float* wc     = (float*)take((size_t)KD*OD*4);
  int* esrc     = (int*)take((size_t)E*4);
  unsigned short* h2 = (unsigned short*)take((size_t)N*OD*2);
  (void)ws_size; (void)out_size; (void)n_in;

  float* out = (float*)d_out;

  hipMemsetAsync(outdeg, 0, (size_t)(zero_end - (char*)outdeg), stream);

  int eb = (E + 255)/256;
  k_degrees<<<eb, 256, 0, stream>>>(src, dst, outdeg, indeg, E);
  k_wc<<<(KD*OD)/256, 256, 0, stream>>>(st_param, weight, wc);
  k_norm<<<(N+255)/256, 256, 0, stream>>>(outdeg, norm_src, N);
  dim3 gg((N+BM-1)/BM, OD/BN);
  k_gemm<<<gg, 256, 0, stream>>>(feat, wc, norm_src, h2, N);
  int nb = (N + 1023)/1024;
  k_scan1<<<nb, 256, 0, stream>>>(indeg, bsum, N);
  k_scan2<<<1, 64, 0, stream>>>(bsum, boff, nb, offsets, N);
  k_scan3<<<nb, 256, 0, stream>>>(indeg, boff, offsets, N);
  k_scatter<<<eb, 256, 0, stream>>>(src, dst, offsets, cursor, esrc, E);
  k_agg<<<(N+3)/4, 256, 0, stream>>>(h2, offsets, esrc, indeg, bias, out, N);
}

// Round 2
// 884.659 us; speedup vs baseline: 1.2392x; 1.2392x over previous
//
#include <hip/hip_runtime.h>

#define T_ 4
#define FI_ 128
#define FO_ 64
#define KD 512     // T*FI
#define OD 256     // T*FO

typedef __attribute__((ext_vector_type(8))) short bf16x8;
typedef __attribute__((ext_vector_type(4))) float f32x4;

static __device__ __forceinline__ float bf2f(unsigned short u){
  return __uint_as_float(((unsigned int)u) << 16);
}
static __device__ __forceinline__ unsigned short f2bf(float f){
  unsigned int u = __float_as_uint(f);
  u += 0x7FFFu + ((u >> 16) & 1u);
  return (unsigned short)(u >> 16);
}

// ---- degree histogram ----
__global__ __launch_bounds__(256) void k_degrees(const int* __restrict__ src,
    const int* __restrict__ dst, int* __restrict__ outdeg, int* __restrict__ indeg, int e)
{
  int i = blockIdx.x*256 + threadIdx.x;
  if (i < e){
    atomicAdd(&outdeg[src[i]], 1);
    atomicAdd(&indeg[dst[i]], 1);
  }
}

// ---- combined weight, bf16 TRANSPOSED: wcT[(t*FO+o)][s*FI+f] = st_m[t][s]*weight[t][f][o] ----
__global__ __launch_bounds__(256) void k_wc(const float* __restrict__ st_param,
    const float* __restrict__ weight, unsigned short* __restrict__ wcT)
{
  int idx = blockIdx.x*256 + threadIdx.x;   // 256*512 total, exact grid
  int c = idx >> 9, r = idx & 511;          // c = out col (t,o), r = in row (s,f)
  int s = r >> 7, f = r & 127, t = c >> 6, o = c & 63;
  float p0 = st_param[t*4+0], p1 = st_param[t*4+1], p2 = st_param[t*4+2], p3 = st_param[t*4+3];
  float m = fmaxf(fmaxf(p0,p1), fmaxf(p2,p3));
  float e0 = expf(p0-m), e1 = expf(p1-m), e2 = expf(p2-m), e3 = expf(p3-m);
  float sum = e0+e1+e2+e3;
  float sel = (s==0)?e0:((s==1)?e1:((s==2)?e2:e3));
  wcT[idx] = f2bf((sel/sum) * weight[(t*FI_+f)*FO_ + o]);
}

// ---- norm_src = clip(outdeg,1)^-0.5 ----
__global__ __launch_bounds__(256) void k_norm(const int* __restrict__ outdeg,
    float* __restrict__ norm_src, int n)
{
  int i = blockIdx.x*256 + threadIdx.x;
  if (i < n){
    int d = outdeg[i]; if (d < 1) d = 1;
    norm_src[i] = rsqrtf((float)d);
  }
}

// ---- MFMA bf16 GEMM: h2[n][256] = bf16(feat[n]*norm_src[n]) @ wcT^T, stored bf16 ----
// BM=64, BN=256 (full width, feat read once), BK=64. 4 waves, each owns 64x64.
#define GBM 64
#define GBK 64
#define ALD 72            // 64 + 8 pad (16B-aligned rows, stride 144B)
#define BLD 72

__global__ __launch_bounds__(256) void k_gemm_mfma(
    const float* __restrict__ feat, const unsigned short* __restrict__ wcT,
    const float* __restrict__ norm_src, unsigned short* __restrict__ h2, int n)
{
  __shared__ unsigned short As[GBM][ALD];   // 64*72*2 = 9216 B
  __shared__ unsigned short Bs[OD][BLD];    // 256*72*2 = 36864 B
  const int row0 = blockIdx.x*GBM;
  const int t = threadIdx.x;
  const int wave = t >> 6, lane = t & 63;
  const int wcol0 = wave*64;
  const int l15 = lane & 15, l4 = lane >> 4;

  f32x4 acc[4][4] = {};   // [m-frag][n-frag]

  for (int k0 = 0; k0 < KD; k0 += GBK){
    // --- load A tile: 64 rows x 64 fp32 cols -> scale -> bf16 LDS ---
    #pragma unroll
    for (int i = 0; i < 4; i++){
      int flat = t + 256*i;          // 1024 float4 chunks
      int r = flat >> 4, c4 = flat & 15;
      int gr = row0 + r;
      float4 v = {0.f,0.f,0.f,0.f};
      if (gr < n){
        v = *(const float4*)(feat + (size_t)gr*KD + k0 + c4*4);
        float ns = norm_src[gr];
        v.x *= ns; v.y *= ns; v.z *= ns; v.w *= ns;
      }
      ushort4 b;
      b.x = f2bf(v.x); b.y = f2bf(v.y); b.z = f2bf(v.z); b.w = f2bf(v.w);
      *(ushort4*)(&As[r][c4*4]) = b;
    }
    // --- load B tile: 256 cols x 64 k bf16 (wcT rows are k-contiguous) ---
    #pragma unroll
    for (int i = 0; i < 8; i++){
      int flat = t + 256*i;          // 2048 16B chunks
      int r = flat >> 3, c = flat & 7;
      uint4 v = *(const uint4*)(wcT + (size_t)r*KD + k0 + c*8);
      *(uint4*)(&Bs[r][c*8]) = v;
    }
    __syncthreads();
    // --- MFMA: 2 k-slices of 32 ---
    #pragma unroll
    for (int ks = 0; ks < 2; ks++){
      bf16x8 af[4], bf[4];
      #pragma unroll
      for (int m = 0; m < 4; m++)
        af[m] = *(const bf16x8*)(&As[m*16 + l15][ks*32 + l4*8]);
      #pragma unroll
      for (int nn = 0; nn < 4; nn++)
        bf[nn] = *(const bf16x8*)(&Bs[wcol0 + nn*16 + l15][ks*32 + l4*8]);
      #pragma unroll
      for (int m = 0; m < 4; m++)
        #pragma unroll
        for (int nn = 0; nn < 4; nn++)
          acc[m][nn] = __builtin_amdgcn_mfma_f32_16x16x32_bf16(af[m], bf[nn], acc[m][nn], 0, 0, 0);
    }
    __syncthreads();
  }
  // --- epilogue: C/D layout col=lane&15, row=(lane>>4)*4+reg ---
  #pragma unroll
  for (int m = 0; m < 4; m++){
    #pragma unroll
    for (int r = 0; r < 4; r++){
      int row = row0 + m*16 + l4*4 + r;
      if (row < n){
        #pragma unroll
        for (int nn = 0; nn < 4; nn++){
          int col = wcol0 + nn*16 + l15;
          h2[(size_t)row*OD + col] = f2bf(acc[m][nn][r]);
        }
      }
    }
  }
}

// ---- scan kernels: exclusive prefix over indeg -> CSR offsets ----
__global__ __launch_bounds__(256) void k_scan1(const int* __restrict__ cnt,
    int* __restrict__ bsum, int n)
{
  __shared__ int wsums[4];
  int b = blockIdx.x, t = threadIdx.x;
  int base = b*1024 + t*4;
  int s = 0;
  #pragma unroll
  for (int i = 0; i < 4; i++){ int idx = base+i; if (idx < n) s += cnt[idx]; }
  #pragma unroll
  for (int d = 1; d < 64; d <<= 1) s += __shfl_xor(s, d);
  if ((t & 63) == 0) wsums[t>>6] = s;
  __syncthreads();
  if (t == 0) bsum[b] = wsums[0]+wsums[1]+wsums[2]+wsums[3];
}

__global__ void k_scan2(const int* __restrict__ bsum, int* __restrict__ boff,
                        int nb, int* __restrict__ offsets, int n)
{
  int lane = threadIdx.x;  // 64 threads, 1 block
  int running = 0;
  for (int base = 0; base < nb; base += 64){
    int v = (base+lane < nb) ? bsum[base+lane] : 0;
    int x = v;
    #pragma unroll
    for (int d = 1; d < 64; d <<= 1){ int y = __shfl_up(x, d); if (lane >= d) x += y; }
    if (base+lane < nb) boff[base+lane] = running + x - v;
    running += __shfl(x, 63);
  }
  if (lane == 0) offsets[n] = running;   // = E
}

__global__ __launch_bounds__(256) void k_scan3(const int* __restrict__ cnt,
    const int* __restrict__ boff, int* __restrict__ offsets, int n)
{
  __shared__ int wsum[4], woff[4];
  int b = blockIdx.x, t = threadIdx.x, lane = t & 63, w = t >> 6;
  int base = b*1024 + t*4;
  int c[4]; int s = 0;
  #pragma unroll
  for (int i = 0; i < 4; i++){ c[i] = (base+i < n) ? cnt[base+i] : 0; s += c[i]; }
  int x = s;
  #pragma unroll
  for (int d = 1; d < 64; d <<= 1){ int y = __shfl_up(x, d); if (lane >= d) x += y; }
  if (lane == 63) wsum[w] = x;
  __syncthreads();
  if (t == 0){ int r = 0; for (int j = 0; j < 4; j++){ woff[j] = r; r += wsum[j]; } }
  __syncthreads();
  int excl = boff[b] + woff[w] + (x - s);
  #pragma unroll
  for (int i = 0; i < 4; i++){
    if (base+i < n) offsets[base+i] = excl;
    excl += c[i];
  }
}

// ---- counting-sort scatter: edges grouped by dst ----
__global__ __launch_bounds__(256) void k_scatter(const int* __restrict__ src,
    const int* __restrict__ dst, const int* __restrict__ offsets,
    int* __restrict__ cursor, int* __restrict__ esrc, int e)
{
  int i = blockIdx.x*256 + threadIdx.x;
  if (i < e){
    int d = dst[i];
    int pos = offsets[d] + atomicAdd(&cursor[d], 1);
    esrc[pos] = src[i];
  }
}

// ---- aggregation: one wave per dst node, register accumulation (no atomics) ----
__global__ __launch_bounds__(256) void k_agg(const unsigned short* __restrict__ h2,
    const int* __restrict__ offsets, const int* __restrict__ esrc,
    const int* __restrict__ indeg, const float* __restrict__ bias,
    float* __restrict__ out, int n)
{
  int node = (blockIdx.x*256 + threadIdx.x) >> 6;
  int lane = threadIdx.x & 63;
  if (node >= n) return;
  int beg = offsets[node], end = offsets[node+1];
  float ax = 0.f, ay = 0.f, az = 0.f, aw = 0.f;
  for (int i = beg; i < end; ++i){
    int s = esrc[i];
    ushort4 v = *(const ushort4*)(h2 + (size_t)s*OD + lane*4);
    ax += bf2f(v.x); ay += bf2f(v.y); az += bf2f(v.z); aw += bf2f(v.w);
  }
  int d = indeg[node]; if (d < 1) d = 1;
  float nd = rsqrtf((float)d);
  float4 bz = *(const float4*)(bias + lane*4);
  float4 o;
  o.x = ax*nd + bz.x; o.y = ay*nd + bz.y;
  o.z = az*nd + bz.z; o.w = aw*nd + bz.w;
  *(float4*)(out + (size_t)node*OD + lane*4) = o;
}

extern "C" void kernel_launch(void* const* d_in, const int* in_sizes, int n_in,
                              void* d_out, int out_size, void* d_ws, size_t ws_size,
                              hipStream_t stream)
{
  const float* feat     = (const float*)d_in[0];
  const float* weight   = (const float*)d_in[1];
  const float* bias     = (const float*)d_in[2];
  const float* st_param = (const float*)d_in[3];
  const int*   src      = (const int*)d_in[4];
  const int*   dst      = (const int*)d_in[5];
  const int N = in_sizes[0] / KD;
  const int E = in_sizes[4];

  char* w = (char*)d_ws;
  size_t off = 0;
  auto take = [&](size_t bytes) -> char* {
    char* p = w + off;
    off = (off + bytes + 255) & ~(size_t)255;
    return p;
  };
  int* outdeg   = (int*)take((size_t)N*4);
  int* indeg    = (int*)take((size_t)N*4);
  int* cursor   = (int*)take((size_t)N*4);
  char* zero_end = w + off;
  int* offsets  = (int*)take((size_t)(N+1)*4);
  int* bsum     = (int*)take(512*4);
  int* boff     = (int*)take(512*4);
  float* norm_src = (float*)take((size_t)N*4);
  unsigned short* wcT = (unsigned short*)take((size_t)KD*OD*2);
  int* esrc     = (int*)take((size_t)E*4);
  unsigned short* h2 = (unsigned short*)take((size_t)N*OD*2);
  (void)ws_size; (void)out_size; (void)n_in;

  float* out = (float*)d_out;

  hipMemsetAsync(outdeg, 0, (size_t)(zero_end - (char*)outdeg), stream);

  int eb = (E + 255)/256;
  k_degrees<<<eb, 256, 0, stream>>>(src, dst, outdeg, indeg, E);
  k_wc<<<(KD*OD)/256, 256, 0, stream>>>(st_param, weight, wcT);
  k_norm<<<(N+255)/256, 256, 0, stream>>>(outdeg, norm_src, N);
  k_gemm_mfma<<<(N+GBM-1)/GBM, 256, 0, stream>>>(feat, wcT, norm_src, h2, N);
  int nb = (N + 1023)/1024;
  k_scan1<<<nb, 256, 0, stream>>>(indeg, bsum, N);
  k_scan2<<<1, 64, 0, stream>>>(bsum, boff, nb, offsets, N);
  k_scan3<<<nb, 256, 0, stream>>>(indeg, boff, offsets, N);
  k_scatter<<<eb, 256, 0, stream>>>(src, dst, offsets, cursor, esrc, E);
  k_agg<<<(N+3)/4, 256, 0, stream>>>(h2, offsets, esrc, indeg, bias, out, N);
}

// Round 3
// 799.746 us; speedup vs baseline: 1.3707x; 1.1062x over previous
//
#include <hip/hip_runtime.h>

#define T_ 4
#define FI_ 128
#define FO_ 64
#define KD 512     // T*FI
#define OD 256     // T*FO

typedef __attribute__((ext_vector_type(8))) short bf16x8;
typedef __attribute__((ext_vector_type(4))) float f32x4;

static __device__ __forceinline__ float bf2f(unsigned short u){
  return __uint_as_float(((unsigned int)u) << 16);
}
static __device__ __forceinline__ unsigned short f2bf(float f){
  unsigned int u = __float_as_uint(f);
  u += 0x7FFFu + ((u >> 16) & 1u);
  return (unsigned short)(u >> 16);
}

// ---- degree histogram ----
__global__ __launch_bounds__(256) void k_degrees(const int* __restrict__ src,
    const int* __restrict__ dst, int* __restrict__ outdeg, int* __restrict__ indeg, int e)
{
  int i = blockIdx.x*256 + threadIdx.x;
  if (i < e){
    atomicAdd(&outdeg[src[i]], 1);
    atomicAdd(&indeg[dst[i]], 1);
  }
}

// ---- combined weight, bf16 TRANSPOSED: wcT[(t*FO+o)][s*FI+f] = st_m[t][s]*weight[t][f][o] ----
__global__ __launch_bounds__(256) void k_wc(const float* __restrict__ st_param,
    const float* __restrict__ weight, unsigned short* __restrict__ wcT)
{
  int idx = blockIdx.x*256 + threadIdx.x;   // 256*512 total, exact grid
  int c = idx >> 9, r = idx & 511;          // c = out col (t,o), r = in row (s,f)
  int s = r >> 7, f = r & 127, t = c >> 6, o = c & 63;
  float p0 = st_param[t*4+0], p1 = st_param[t*4+1], p2 = st_param[t*4+2], p3 = st_param[t*4+3];
  float m = fmaxf(fmaxf(p0,p1), fmaxf(p2,p3));
  float e0 = expf(p0-m), e1 = expf(p1-m), e2 = expf(p2-m), e3 = expf(p3-m);
  float sum = e0+e1+e2+e3;
  float sel = (s==0)?e0:((s==1)?e1:((s==2)?e2:e3));
  wcT[idx] = f2bf((sel/sum) * weight[(t*FI_+f)*FO_ + o]);
}

// ---- norm_src = clip(outdeg,1)^-0.5 ----
__global__ __launch_bounds__(256) void k_norm(const int* __restrict__ outdeg,
    float* __restrict__ norm_src, int n)
{
  int i = blockIdx.x*256 + threadIdx.x;
  if (i < n){
    int d = outdeg[i]; if (d < 1) d = 1;
    norm_src[i] = rsqrtf((float)d);
  }
}

// ---- MFMA bf16 GEMM: h2[n][256] = bf16(feat[n]*norm_src[n]) @ wcT^T, stored bf16 ----
#define GBM 64
#define GBK 64
#define ALD 72
#define BLD 72

__global__ __launch_bounds__(256) void k_gemm_mfma(
    const float* __restrict__ feat, const unsigned short* __restrict__ wcT,
    const float* __restrict__ norm_src, unsigned short* __restrict__ h2, int n)
{
  __shared__ unsigned short As[GBM][ALD];   // 64*72*2 = 9216 B
  __shared__ unsigned short Bs[OD][BLD];    // 256*72*2 = 36864 B
  const int row0 = blockIdx.x*GBM;
  const int t = threadIdx.x;
  const int wave = t >> 6, lane = t & 63;
  const int wcol0 = wave*64;
  const int l15 = lane & 15, l4 = lane >> 4;

  f32x4 acc[4][4] = {};   // [m-frag][n-frag]

  for (int k0 = 0; k0 < KD; k0 += GBK){
    #pragma unroll
    for (int i = 0; i < 4; i++){
      int flat = t + 256*i;          // 1024 float4 chunks
      int r = flat >> 4, c4 = flat & 15;
      int gr = row0 + r;
      float4 v = {0.f,0.f,0.f,0.f};
      if (gr < n){
        v = *(const float4*)(feat + (size_t)gr*KD + k0 + c4*4);
        float ns = norm_src[gr];
        v.x *= ns; v.y *= ns; v.z *= ns; v.w *= ns;
      }
      ushort4 b;
      b.x = f2bf(v.x); b.y = f2bf(v.y); b.z = f2bf(v.z); b.w = f2bf(v.w);
      *(ushort4*)(&As[r][c4*4]) = b;
    }
    #pragma unroll
    for (int i = 0; i < 8; i++){
      int flat = t + 256*i;          // 2048 16B chunks
      int r = flat >> 3, c = flat & 7;
      uint4 v = *(const uint4*)(wcT + (size_t)r*KD + k0 + c*8);
      *(uint4*)(&Bs[r][c*8]) = v;
    }
    __syncthreads();
    #pragma unroll
    for (int ks = 0; ks < 2; ks++){
      bf16x8 af[4], bfr[4];
      #pragma unroll
      for (int m = 0; m < 4; m++)
        af[m] = *(const bf16x8*)(&As[m*16 + l15][ks*32 + l4*8]);
      #pragma unroll
      for (int nn = 0; nn < 4; nn++)
        bfr[nn] = *(const bf16x8*)(&Bs[wcol0 + nn*16 + l15][ks*32 + l4*8]);
      #pragma unroll
      for (int m = 0; m < 4; m++)
        #pragma unroll
        for (int nn = 0; nn < 4; nn++)
          acc[m][nn] = __builtin_amdgcn_mfma_f32_16x16x32_bf16(af[m], bfr[nn], acc[m][nn], 0, 0, 0);
    }
    __syncthreads();
  }
  #pragma unroll
  for (int m = 0; m < 4; m++){
    #pragma unroll
    for (int r = 0; r < 4; r++){
      int row = row0 + m*16 + l4*4 + r;
      if (row < n){
        #pragma unroll
        for (int nn = 0; nn < 4; nn++){
          int col = wcol0 + nn*16 + l15;
          h2[(size_t)row*OD + col] = f2bf(acc[m][nn][r]);
        }
      }
    }
  }
}

// ---- scan kernels ----
__global__ __launch_bounds__(256) void k_scan1(const int* __restrict__ cnt,
    int* __restrict__ bsum, int n)
{
  __shared__ int wsums[4];
  int b = blockIdx.x, t = threadIdx.x;
  int base = b*1024 + t*4;
  int s = 0;
  #pragma unroll
  for (int i = 0; i < 4; i++){ int idx = base+i; if (idx < n) s += cnt[idx]; }
  #pragma unroll
  for (int d = 1; d < 64; d <<= 1) s += __shfl_xor(s, d);
  if ((t & 63) == 0) wsums[t>>6] = s;
  __syncthreads();
  if (t == 0) bsum[b] = wsums[0]+wsums[1]+wsums[2]+wsums[3];
}

__global__ void k_scan2(const int* __restrict__ bsum, int* __restrict__ boff,
                        int nb, int* __restrict__ offsets, int n)
{
  int lane = threadIdx.x;  // 64 threads, 1 block
  int running = 0;
  for (int base = 0; base < nb; base += 64){
    int v = (base+lane < nb) ? bsum[base+lane] : 0;
    int x = v;
    #pragma unroll
    for (int d = 1; d < 64; d <<= 1){ int y = __shfl_up(x, d); if (lane >= d) x += y; }
    if (base+lane < nb) boff[base+lane] = running + x - v;
    running += __shfl(x, 63);
  }
  if (lane == 0) offsets[n] = running;   // = E
}

__global__ __launch_bounds__(256) void k_scan3(const int* __restrict__ cnt,
    const int* __restrict__ boff, int* __restrict__ offsets, int n)
{
  __shared__ int wsum[4], woff[4];
  int b = blockIdx.x, t = threadIdx.x, lane = t & 63, w = t >> 6;
  int base = b*1024 + t*4;
  int c[4]; int s = 0;
  #pragma unroll
  for (int i = 0; i < 4; i++){ c[i] = (base+i < n) ? cnt[base+i] : 0; s += c[i]; }
  int x = s;
  #pragma unroll
  for (int d = 1; d < 64; d <<= 1){ int y = __shfl_up(x, d); if (lane >= d) x += y; }
  if (lane == 63) wsum[w] = x;
  __syncthreads();
  if (t == 0){ int r = 0; for (int j = 0; j < 4; j++){ woff[j] = r; r += wsum[j]; } }
  __syncthreads();
  int excl = boff[b] + woff[w] + (x - s);
  #pragma unroll
  for (int i = 0; i < 4; i++){
    if (base+i < n) offsets[base+i] = excl;
    excl += c[i];
  }
}

// ---- counting-sort scatter ----
__global__ __launch_bounds__(256) void k_scatter(const int* __restrict__ src,
    const int* __restrict__ dst, const int* __restrict__ offsets,
    int* __restrict__ cursor, int* __restrict__ esrc, int e)
{
  int i = blockIdx.x*256 + threadIdx.x;
  if (i < e){
    int d = dst[i];
    int pos = offsets[d] + atomicAdd(&cursor[d], 1);
    esrc[pos] = src[i];
  }
}

// ---- aggregation v2: one wave per dst node; 2 edges per gather pass (32 lanes x 16B each),
//      unrolled 4 -> 8 edges (4 KB) in flight per wave ----
__global__ __launch_bounds__(256) void k_agg(const unsigned short* __restrict__ h2,
    const int* __restrict__ offsets, const int* __restrict__ esrc,
    const int* __restrict__ indeg, const float* __restrict__ bias,
    float* __restrict__ out, int n)
{
  int node = (blockIdx.x*256 + threadIdx.x) >> 6;
  int lane = threadIdx.x & 63;
  if (node >= n) return;
  const int half = lane >> 5;        // which edge of the pair
  const int col8 = lane & 31;        // owns cols [col8*8, col8*8+8)
  int beg = offsets[node], end = offsets[node+1];

  float a0=0.f,a1=0.f,a2=0.f,a3=0.f,a4=0.f,a5=0.f,a6=0.f,a7=0.f;

  #define ACC(V) { \
    unsigned short s0 = (unsigned short)((V).x & 0xFFFFu), s1 = (unsigned short)((V).x >> 16); \
    unsigned short s2 = (unsigned short)((V).y & 0xFFFFu), s3 = (unsigned short)((V).y >> 16); \
    unsigned short s4 = (unsigned short)((V).z & 0xFFFFu), s5 = (unsigned short)((V).z >> 16); \
    unsigned short s6 = (unsigned short)((V).w & 0xFFFFu), s7 = (unsigned short)((V).w >> 16); \
    a0 += bf2f(s0); a1 += bf2f(s1); a2 += bf2f(s2); a3 += bf2f(s3); \
    a4 += bf2f(s4); a5 += bf2f(s5); a6 += bf2f(s6); a7 += bf2f(s7); }

  int i = beg;
  for (; i + 8 <= end; i += 8){
    int e0 = esrc[i     + half];
    int e1 = esrc[i + 2 + half];
    int e2 = esrc[i + 4 + half];
    int e3 = esrc[i + 6 + half];
    uint4 v0 = *(const uint4*)(h2 + (size_t)e0*OD + col8*8);
    uint4 v1 = *(const uint4*)(h2 + (size_t)e1*OD + col8*8);
    uint4 v2 = *(const uint4*)(h2 + (size_t)e2*OD + col8*8);
    uint4 v3 = *(const uint4*)(h2 + (size_t)e3*OD + col8*8);
    ACC(v0); ACC(v1); ACC(v2); ACC(v3);
  }
  for (; i + 2 <= end; i += 2){
    int e = esrc[i + half];
    uint4 v = *(const uint4*)(h2 + (size_t)e*OD + col8*8);
    ACC(v);
  }
  if (i < end && half == 0){
    int e = esrc[i];
    uint4 v = *(const uint4*)(h2 + (size_t)e*OD + col8*8);
    ACC(v);
  }
  #undef ACC

  // merge the two halves (lanes l and l^32 hold the same 8 columns)
  a0 += __shfl_xor(a0, 32); a1 += __shfl_xor(a1, 32);
  a2 += __shfl_xor(a2, 32); a3 += __shfl_xor(a3, 32);
  a4 += __shfl_xor(a4, 32); a5 += __shfl_xor(a5, 32);
  a6 += __shfl_xor(a6, 32); a7 += __shfl_xor(a7, 32);

  int d = indeg[node]; if (d < 1) d = 1;
  float nd = rsqrtf((float)d);
  // each lane writes 4 floats: cols col8*8 + half*4 .. +3
  int c0 = col8*8 + half*4;
  const float* bz = bias + c0;
  float4 o;
  if (half == 0){
    o.x = a0*nd + bz[0]; o.y = a1*nd + bz[1];
    o.z = a2*nd + bz[2]; o.w = a3*nd + bz[3];
  } else {
    o.x = a4*nd + bz[0]; o.y = a5*nd + bz[1];
    o.z = a6*nd + bz[2]; o.w = a7*nd + bz[3];
  }
  *(float4*)(out + (size_t)node*OD + c0) = o;
}

extern "C" void kernel_launch(void* const* d_in, const int* in_sizes, int n_in,
                              void* d_out, int out_size, void* d_ws, size_t ws_size,
                              hipStream_t stream)
{
  const float* feat     = (const float*)d_in[0];
  const float* weight   = (const float*)d_in[1];
  const float* bias     = (const float*)d_in[2];
  const float* st_param = (const float*)d_in[3];
  const int*   src      = (const int*)d_in[4];
  const int*   dst      = (const int*)d_in[5];
  const int N = in_sizes[0] / KD;
  const int E = in_sizes[4];

  char* w = (char*)d_ws;
  size_t off = 0;
  auto take = [&](size_t bytes) -> char* {
    char* p = w + off;
    off = (off + bytes + 255) & ~(size_t)255;
    return p;
  };
  int* outdeg   = (int*)take((size_t)N*4);
  int* indeg    = (int*)take((size_t)N*4);
  int* cursor   = (int*)take((size_t)N*4);
  char* zero_end = w + off;
  int* offsets  = (int*)take((size_t)(N+1)*4);
  int* bsum     = (int*)take(512*4);
  int* boff     = (int*)take(512*4);
  float* norm_src = (float*)take((size_t)N*4);
  unsigned short* wcT = (unsigned short*)take((size_t)KD*OD*2);
  int* esrc     = (int*)take((size_t)E*4);
  unsigned short* h2 = (unsigned short*)take((size_t)N*OD*2);
  (void)ws_size; (void)out_size; (void)n_in;

  float* out = (float*)d_out;

  hipMemsetAsync(outdeg, 0, (size_t)(zero_end - (char*)outdeg), stream);

  int eb = (E + 255)/256;
  k_degrees<<<eb, 256, 0, stream>>>(src, dst, outdeg, indeg, E);
  k_wc<<<(KD*OD)/256, 256, 0, stream>>>(st_param, weight, wcT);
  k_norm<<<(N+255)/256, 256, 0, stream>>>(outdeg, norm_src, N);
  k_gemm_mfma<<<(N+GBM-1)/GBM, 256, 0, stream>>>(feat, wcT, norm_src, h2, N);
  int nb = (N + 1023)/1024;
  k_scan1<<<nb, 256, 0, stream>>>(indeg, bsum, N);
  k_scan2<<<1, 64, 0, stream>>>(bsum, boff, nb, offsets, N);
  k_scan3<<<nb, 256, 0, stream>>>(indeg, boff, offsets, N);
  k_scatter<<<eb, 256, 0, stream>>>(src, dst, offsets, cursor, esrc, E);
  k_agg<<<(N+3)/4, 256, 0, stream>>>(h2, offsets, esrc, indeg, bias, out, N);
}

// Round 4
// 762.509 us; speedup vs baseline: 1.4377x; 1.0488x over previous
//
#include <hip/hip_runtime.h>

#define T_ 4
#define FI_ 128
#define FO_ 64
#define KD 512     // T*FI
#define OD 256     // T*FO
#define NSH 8      // XCD shards

typedef __attribute__((ext_vector_type(8))) short bf16x8;
typedef __attribute__((ext_vector_type(4))) float f32x4;

static __device__ __forceinline__ float bf2f(unsigned short u){
  return __uint_as_float(((unsigned int)u) << 16);
}
static __device__ __forceinline__ unsigned short f2bf(float f){
  unsigned int u = __float_as_uint(f);
  u += 0x7FFFu + ((u >> 16) & 1u);
  return (unsigned short)(u >> 16);
}

// ---- XCD-sharded degree histogram: shard = blockIdx&7 stays in one XCD's L2 ----
__global__ __launch_bounds__(256) void k_degrees(const int* __restrict__ src,
    const int* __restrict__ dst, int* __restrict__ outdeg8, int* __restrict__ indeg8,
    int e, int n)
{
  int base = (blockIdx.x*256 + threadIdx.x)*4;
  int sN = (blockIdx.x & (NSH-1)) * n;
  if (base + 3 < e){
    int4 a = *(const int4*)(src + base);
    int4 b = *(const int4*)(dst + base);
    atomicAdd(&outdeg8[sN + a.x], 1); atomicAdd(&outdeg8[sN + a.y], 1);
    atomicAdd(&outdeg8[sN + a.z], 1); atomicAdd(&outdeg8[sN + a.w], 1);
    atomicAdd(&indeg8[sN + b.x], 1); atomicAdd(&indeg8[sN + b.y], 1);
    atomicAdd(&indeg8[sN + b.z], 1); atomicAdd(&indeg8[sN + b.w], 1);
  } else {
    for (int i = base; i < e; i++){
      atomicAdd(&outdeg8[sN + src[i]], 1);
      atomicAdd(&indeg8[sN + dst[i]], 1);
    }
  }
}

// ---- reduce shards -> norm_src, indeg, per-shard exclusive cum ----
__global__ __launch_bounds__(256) void k_red(const int* __restrict__ outdeg8,
    const int* __restrict__ indeg8, float* __restrict__ norm_src,
    int* __restrict__ indeg, int* __restrict__ cum8, int n)
{
  int i = blockIdx.x*256 + threadIdx.x;
  if (i >= n) return;
  int od = 0;
  #pragma unroll
  for (int s = 0; s < NSH; s++) od += outdeg8[s*n + i];
  if (od < 1) od = 1;
  norm_src[i] = rsqrtf((float)od);
  int c = 0;
  #pragma unroll
  for (int s = 0; s < NSH; s++){
    cum8[s*n + i] = c;
    c += indeg8[s*n + i];
  }
  indeg[i] = c;
}

// ---- combined weight, bf16 TRANSPOSED: wcT[(t*FO+o)][s*FI+f] = st_m[t][s]*weight[t][f][o] ----
__global__ __launch_bounds__(256) void k_wc(const float* __restrict__ st_param,
    const float* __restrict__ weight, unsigned short* __restrict__ wcT)
{
  int idx = blockIdx.x*256 + threadIdx.x;   // 256*512 total, exact grid
  int c = idx >> 9, r = idx & 511;          // c = out col (t,o), r = in row (s,f)
  int s = r >> 7, f = r & 127, t = c >> 6, o = c & 63;
  float p0 = st_param[t*4+0], p1 = st_param[t*4+1], p2 = st_param[t*4+2], p3 = st_param[t*4+3];
  float m = fmaxf(fmaxf(p0,p1), fmaxf(p2,p3));
  float e0 = expf(p0-m), e1 = expf(p1-m), e2 = expf(p2-m), e3 = expf(p3-m);
  float sum = e0+e1+e2+e3;
  float sel = (s==0)?e0:((s==1)?e1:((s==2)?e2:e3));
  wcT[idx] = f2bf((sel/sum) * weight[(t*FI_+f)*FO_ + o]);
}

// ---- MFMA bf16 GEMM: h2[n][256] = bf16(feat[n]*norm_src[n]) @ wcT^T, stored bf16 ----
#define GBM 64
#define GBK 64
#define ALD 72
#define BLD 72

__global__ __launch_bounds__(256) void k_gemm_mfma(
    const float* __restrict__ feat, const unsigned short* __restrict__ wcT,
    const float* __restrict__ norm_src, unsigned short* __restrict__ h2, int n)
{
  __shared__ unsigned short As[GBM][ALD];   // 64*72*2 = 9216 B
  __shared__ unsigned short Bs[OD][BLD];    // 256*72*2 = 36864 B
  const int row0 = blockIdx.x*GBM;
  const int t = threadIdx.x;
  const int wave = t >> 6, lane = t & 63;
  const int wcol0 = wave*64;
  const int l15 = lane & 15, l4 = lane >> 4;

  f32x4 acc[4][4] = {};   // [m-frag][n-frag]

  for (int k0 = 0; k0 < KD; k0 += GBK){
    #pragma unroll
    for (int i = 0; i < 4; i++){
      int flat = t + 256*i;          // 1024 float4 chunks
      int r = flat >> 4, c4 = flat & 15;
      int gr = row0 + r;
      float4 v = {0.f,0.f,0.f,0.f};
      if (gr < n){
        v = *(const float4*)(feat + (size_t)gr*KD + k0 + c4*4);
        float ns = norm_src[gr];
        v.x *= ns; v.y *= ns; v.z *= ns; v.w *= ns;
      }
      ushort4 b;
      b.x = f2bf(v.x); b.y = f2bf(v.y); b.z = f2bf(v.z); b.w = f2bf(v.w);
      *(ushort4*)(&As[r][c4*4]) = b;
    }
    #pragma unroll
    for (int i = 0; i < 8; i++){
      int flat = t + 256*i;          // 2048 16B chunks
      int r = flat >> 3, c = flat & 7;
      uint4 v = *(const uint4*)(wcT + (size_t)r*KD + k0 + c*8);
      *(uint4*)(&Bs[r][c*8]) = v;
    }
    __syncthreads();
    #pragma unroll
    for (int ks = 0; ks < 2; ks++){
      bf16x8 af[4], bfr[4];
      #pragma unroll
      for (int m = 0; m < 4; m++)
        af[m] = *(const bf16x8*)(&As[m*16 + l15][ks*32 + l4*8]);
      #pragma unroll
      for (int nn = 0; nn < 4; nn++)
        bfr[nn] = *(const bf16x8*)(&Bs[wcol0 + nn*16 + l15][ks*32 + l4*8]);
      #pragma unroll
      for (int m = 0; m < 4; m++)
        #pragma unroll
        for (int nn = 0; nn < 4; nn++)
          acc[m][nn] = __builtin_amdgcn_mfma_f32_16x16x32_bf16(af[m], bfr[nn], acc[m][nn], 0, 0, 0);
    }
    __syncthreads();
  }
  #pragma unroll
  for (int m = 0; m < 4; m++){
    #pragma unroll
    for (int r = 0; r < 4; r++){
      int row = row0 + m*16 + l4*4 + r;
      if (row < n){
        #pragma unroll
        for (int nn = 0; nn < 4; nn++){
          int col = wcol0 + nn*16 + l15;
          h2[(size_t)row*OD + col] = f2bf(acc[m][nn][r]);
        }
      }
    }
  }
}

// ---- scan kernels: exclusive prefix over indeg -> CSR offsets ----
__global__ __launch_bounds__(256) void k_scan1(const int* __restrict__ cnt,
    int* __restrict__ bsum, int n)
{
  __shared__ int wsums[4];
  int b = blockIdx.x, t = threadIdx.x;
  int base = b*1024 + t*4;
  int s = 0;
  #pragma unroll
  for (int i = 0; i < 4; i++){ int idx = base+i; if (idx < n) s += cnt[idx]; }
  #pragma unroll
  for (int d = 1; d < 64; d <<= 1) s += __shfl_xor(s, d);
  if ((t & 63) == 0) wsums[t>>6] = s;
  __syncthreads();
  if (t == 0) bsum[b] = wsums[0]+wsums[1]+wsums[2]+wsums[3];
}

__global__ void k_scan2(const int* __restrict__ bsum, int* __restrict__ boff,
                        int nb, int* __restrict__ offsets, int n)
{
  int lane = threadIdx.x;  // 64 threads, 1 block
  int running = 0;
  for (int base = 0; base < nb; base += 64){
    int v = (base+lane < nb) ? bsum[base+lane] : 0;
    int x = v;
    #pragma unroll
    for (int d = 1; d < 64; d <<= 1){ int y = __shfl_up(x, d); if (lane >= d) x += y; }
    if (base+lane < nb) boff[base+lane] = running + x - v;
    running += __shfl(x, 63);
  }
  if (lane == 0) offsets[n] = running;   // = E
}

__global__ __launch_bounds__(256) void k_scan3(const int* __restrict__ cnt,
    const int* __restrict__ boff, int* __restrict__ offsets, int n)
{
  __shared__ int wsum[4], woff[4];
  int b = blockIdx.x, t = threadIdx.x, lane = t & 63, w = t >> 6;
  int base = b*1024 + t*4;
  int c[4]; int s = 0;
  #pragma unroll
  for (int i = 0; i < 4; i++){ c[i] = (base+i < n) ? cnt[base+i] : 0; s += c[i]; }
  int x = s;
  #pragma unroll
  for (int d = 1; d < 64; d <<= 1){ int y = __shfl_up(x, d); if (lane >= d) x += y; }
  if (lane == 63) wsum[w] = x;
  __syncthreads();
  if (t == 0){ int r = 0; for (int j = 0; j < 4; j++){ woff[j] = r; r += wsum[j]; } }
  __syncthreads();
  int excl = boff[b] + woff[w] + (x - s);
  #pragma unroll
  for (int i = 0; i < 4; i++){
    if (base+i < n) offsets[base+i] = excl;
    excl += c[i];
  }
}

// ---- counting-sort scatter with XCD-sharded cursors (matches k_degrees edge->shard map) ----
__global__ __launch_bounds__(256) void k_scatter(const int* __restrict__ src,
    const int* __restrict__ dst, const int* __restrict__ offsets,
    const int* __restrict__ cum8, int* __restrict__ cursor8,
    int* __restrict__ esrc, int e, int n)
{
  int base = (blockIdx.x*256 + threadIdx.x)*4;
  int sN = (blockIdx.x & (NSH-1)) * n;
  if (base + 3 < e){
    int4 a = *(const int4*)(src + base);
    int4 b = *(const int4*)(dst + base);
    int p0 = offsets[b.x] + cum8[sN + b.x] + atomicAdd(&cursor8[sN + b.x], 1);
    int p1 = offsets[b.y] + cum8[sN + b.y] + atomicAdd(&cursor8[sN + b.y], 1);
    int p2 = offsets[b.z] + cum8[sN + b.z] + atomicAdd(&cursor8[sN + b.z], 1);
    int p3 = offsets[b.w] + cum8[sN + b.w] + atomicAdd(&cursor8[sN + b.w], 1);
    esrc[p0] = a.x; esrc[p1] = a.y; esrc[p2] = a.z; esrc[p3] = a.w;
  } else {
    for (int i = base; i < e; i++){
      int d = dst[i];
      int pos = offsets[d] + cum8[sN + d] + atomicAdd(&cursor8[sN + d], 1);
      esrc[pos] = src[i];
    }
  }
}

// ---- aggregation: one wave per dst node; 2 edges per gather pass (32 lanes x 16B),
//      unrolled 4 -> 8 edges (4 KB) in flight per wave ----
__global__ __launch_bounds__(256) void k_agg(const unsigned short* __restrict__ h2,
    const int* __restrict__ offsets, const int* __restrict__ esrc,
    const int* __restrict__ indeg, const float* __restrict__ bias,
    float* __restrict__ out, int n)
{
  int node = (blockIdx.x*256 + threadIdx.x) >> 6;
  int lane = threadIdx.x & 63;
  if (node >= n) return;
  const int half = lane >> 5;        // which edge of the pair
  const int col8 = lane & 31;        // owns cols [col8*8, col8*8+8)
  int beg = offsets[node], end = offsets[node+1];

  float a0=0.f,a1=0.f,a2=0.f,a3=0.f,a4=0.f,a5=0.f,a6=0.f,a7=0.f;

  #define ACC(V) { \
    unsigned short s0 = (unsigned short)((V).x & 0xFFFFu), s1 = (unsigned short)((V).x >> 16); \
    unsigned short s2 = (unsigned short)((V).y & 0xFFFFu), s3 = (unsigned short)((V).y >> 16); \
    unsigned short s4 = (unsigned short)((V).z & 0xFFFFu), s5 = (unsigned short)((V).z >> 16); \
    unsigned short s6 = (unsigned short)((V).w & 0xFFFFu), s7 = (unsigned short)((V).w >> 16); \
    a0 += bf2f(s0); a1 += bf2f(s1); a2 += bf2f(s2); a3 += bf2f(s3); \
    a4 += bf2f(s4); a5 += bf2f(s5); a6 += bf2f(s6); a7 += bf2f(s7); }

  int i = beg;
  for (; i + 8 <= end; i += 8){
    int e0 = esrc[i     + half];
    int e1 = esrc[i + 2 + half];
    int e2 = esrc[i + 4 + half];
    int e3 = esrc[i + 6 + half];
    uint4 v0 = *(const uint4*)(h2 + (size_t)e0*OD + col8*8);
    uint4 v1 = *(const uint4*)(h2 + (size_t)e1*OD + col8*8);
    uint4 v2 = *(const uint4*)(h2 + (size_t)e2*OD + col8*8);
    uint4 v3 = *(const uint4*)(h2 + (size_t)e3*OD + col8*8);
    ACC(v0); ACC(v1); ACC(v2); ACC(v3);
  }
  for (; i + 2 <= end; i += 2){
    int e = esrc[i + half];
    uint4 v = *(const uint4*)(h2 + (size_t)e*OD + col8*8);
    ACC(v);
  }
  if (i < end && half == 0){
    int e = esrc[i];
    uint4 v = *(const uint4*)(h2 + (size_t)e*OD + col8*8);
    ACC(v);
  }
  #undef ACC

  a0 += __shfl_xor(a0, 32); a1 += __shfl_xor(a1, 32);
  a2 += __shfl_xor(a2, 32); a3 += __shfl_xor(a3, 32);
  a4 += __shfl_xor(a4, 32); a5 += __shfl_xor(a5, 32);
  a6 += __shfl_xor(a6, 32); a7 += __shfl_xor(a7, 32);

  int d = indeg[node]; if (d < 1) d = 1;
  float nd = rsqrtf((float)d);
  int c0 = col8*8 + half*4;
  const float* bz = bias + c0;
  float4 o;
  if (half == 0){
    o.x = a0*nd + bz[0]; o.y = a1*nd + bz[1];
    o.z = a2*nd + bz[2]; o.w = a3*nd + bz[3];
  } else {
    o.x = a4*nd + bz[0]; o.y = a5*nd + bz[1];
    o.z = a6*nd + bz[2]; o.w = a7*nd + bz[3];
  }
  *(float4*)(out + (size_t)node*OD + c0) = o;
}

extern "C" void kernel_launch(void* const* d_in, const int* in_sizes, int n_in,
                              void* d_out, int out_size, void* d_ws, size_t ws_size,
                              hipStream_t stream)
{
  const float* feat     = (const float*)d_in[0];
  const float* weight   = (const float*)d_in[1];
  const float* bias     = (const float*)d_in[2];
  const float* st_param = (const float*)d_in[3];
  const int*   src      = (const int*)d_in[4];
  const int*   dst      = (const int*)d_in[5];
  const int N = in_sizes[0] / KD;
  const int E = in_sizes[4];

  char* w = (char*)d_ws;
  size_t off = 0;
  auto take = [&](size_t bytes) -> char* {
    char* p = w + off;
    off = (off + bytes + 255) & ~(size_t)255;
    return p;
  };
  int* outdeg8  = (int*)take((size_t)NSH*N*4);
  int* indeg8   = (int*)take((size_t)NSH*N*4);
  int* cursor8  = (int*)take((size_t)NSH*N*4);
  char* zero_end = w + off;
  int* cum8     = (int*)take((size_t)NSH*N*4);
  int* indeg    = (int*)take((size_t)N*4);
  int* offsets  = (int*)take((size_t)(N+1)*4);
  int* bsum     = (int*)take(512*4);
  int* boff     = (int*)take(512*4);
  float* norm_src = (float*)take((size_t)N*4);
  unsigned short* wcT = (unsigned short*)take((size_t)KD*OD*2);
  int* esrc     = (int*)take((size_t)E*4);
  unsigned short* h2 = (unsigned short*)take((size_t)N*OD*2);
  (void)ws_size; (void)out_size; (void)n_in;

  float* out = (float*)d_out;

  hipMemsetAsync(outdeg8, 0, (size_t)(zero_end - (char*)outdeg8), stream);

  int eb4 = (E + 1023)/1024;            // 4 edges per thread
  k_degrees<<<eb4, 256, 0, stream>>>(src, dst, outdeg8, indeg8, E, N);
  k_wc<<<(KD*OD)/256, 256, 0, stream>>>(st_param, weight, wcT);
  k_red<<<(N+255)/256, 256, 0, stream>>>(outdeg8, indeg8, norm_src, indeg, cum8, N);
  k_gemm_mfma<<<(N+GBM-1)/GBM, 256, 0, stream>>>(feat, wcT, norm_src, h2, N);
  int nb = (N + 1023)/1024;
  k_scan1<<<nb, 256, 0, stream>>>(indeg, bsum, N);
  k_scan2<<<1, 64, 0, stream>>>(bsum, boff, nb, offsets, N);
  k_scan3<<<nb, 256, 0, stream>>>(indeg, boff, offsets, N);
  k_scatter<<<eb4, 256, 0, stream>>>(src, dst, offsets, cum8, cursor8, esrc, E, N);
  k_agg<<<(N+3)/4, 256, 0, stream>>>(h2, offsets, esrc, indeg, bias, out, N);
}

// Round 5
// 697.986 us; speedup vs baseline: 1.5706x; 1.0924x over previous
//
#include <hip/hip_runtime.h>

#define T_ 4
#define FI_ 128
#define FO_ 64
#define KD 512     // T*FI
#define OD 256     // T*FO
#define NSH 8      // XCD shards

typedef __attribute__((ext_vector_type(8))) short bf16x8;
typedef __attribute__((ext_vector_type(4))) float f32x4;

static __device__ __forceinline__ float bf2f(unsigned short u){
  return __uint_as_float(((unsigned int)u) << 16);
}
static __device__ __forceinline__ unsigned short f2bf(float f){
  unsigned int u = __float_as_uint(f);
  u += 0x7FFFu + ((u >> 16) & 1u);
  return (unsigned short)(u >> 16);
}
// true XCC id (0..7) — workgroup-scope atomics to a shard owned by this XCD
// execute & stay in this XCD's L2 (single serialization point => atomicity ok)
static __device__ __forceinline__ int xcc_id(){
  unsigned v;
  asm volatile("s_getreg_b32 %0, hwreg(HW_REG_XCC_ID)" : "=s"(v));
  return (int)(v & 7u);
}
#define WG_ADD(p) __hip_atomic_fetch_add((p), 1, __ATOMIC_RELAXED, __HIP_MEMORY_SCOPE_WORKGROUP)

// ---- degrees + per-edge rank: L2-local atomics, rank packed (xcc<<24)|r ----
__global__ __launch_bounds__(256) void k_degrees(const int* __restrict__ src,
    const int* __restrict__ dst, int* __restrict__ outdeg8, int* __restrict__ indeg8,
    unsigned* __restrict__ epos, int e, int n)
{
  int i0 = (blockIdx.x*256 + threadIdx.x)*4;
  unsigned s = (unsigned)xcc_id();
  int sN = (int)s * n;
  unsigned stag = s << 24;
  if (i0 + 3 < e){
    int4 a = *(const int4*)(src + i0);
    int4 b = *(const int4*)(dst + i0);
    WG_ADD(&outdeg8[sN + a.x]); WG_ADD(&outdeg8[sN + a.y]);
    WG_ADD(&outdeg8[sN + a.z]); WG_ADD(&outdeg8[sN + a.w]);
    unsigned r0 = (unsigned)WG_ADD(&indeg8[sN + b.x]);
    unsigned r1 = (unsigned)WG_ADD(&indeg8[sN + b.y]);
    unsigned r2 = (unsigned)WG_ADD(&indeg8[sN + b.z]);
    unsigned r3 = (unsigned)WG_ADD(&indeg8[sN + b.w]);
    uint4 p; p.x = stag|r0; p.y = stag|r1; p.z = stag|r2; p.w = stag|r3;
    *(uint4*)(epos + i0) = p;
  } else {
    for (int i = i0; i < e; i++){
      WG_ADD(&outdeg8[sN + src[i]]);
      unsigned r = (unsigned)WG_ADD(&indeg8[sN + dst[i]]);
      epos[i] = stag | r;
    }
  }
}

// ---- reduce shards -> norm_src, indeg, per-shard exclusive cum ----
__global__ __launch_bounds__(256) void k_red(const int* __restrict__ outdeg8,
    const int* __restrict__ indeg8, float* __restrict__ norm_src,
    int* __restrict__ indeg, int* __restrict__ cum8, int n)
{
  int i = blockIdx.x*256 + threadIdx.x;
  if (i >= n) return;
  int od = 0;
  #pragma unroll
  for (int s = 0; s < NSH; s++) od += outdeg8[s*n + i];
  if (od < 1) od = 1;
  norm_src[i] = rsqrtf((float)od);
  int c = 0;
  #pragma unroll
  for (int s = 0; s < NSH; s++){
    cum8[s*n + i] = c;
    c += indeg8[s*n + i];
  }
  indeg[i] = c;
}

// ---- combined weight, bf16 TRANSPOSED: wcT[(t*FO+o)][s*FI+f] = st_m[t][s]*weight[t][f][o] ----
__global__ __launch_bounds__(256) void k_wc(const float* __restrict__ st_param,
    const float* __restrict__ weight, unsigned short* __restrict__ wcT)
{
  int idx = blockIdx.x*256 + threadIdx.x;   // 256*512 total, exact grid
  int c = idx >> 9, r = idx & 511;          // c = out col (t,o), r = in row (s,f)
  int s = r >> 7, f = r & 127, t = c >> 6, o = c & 63;
  float p0 = st_param[t*4+0], p1 = st_param[t*4+1], p2 = st_param[t*4+2], p3 = st_param[t*4+3];
  float m = fmaxf(fmaxf(p0,p1), fmaxf(p2,p3));
  float e0 = expf(p0-m), e1 = expf(p1-m), e2 = expf(p2-m), e3 = expf(p3-m);
  float sum = e0+e1+e2+e3;
  float sel = (s==0)?e0:((s==1)?e1:((s==2)?e2:e3));
  wcT[idx] = f2bf((sel/sum) * weight[(t*FI_+f)*FO_ + o]);
}

// ---- MFMA bf16 GEMM: h2[n][256] = bf16(feat[n]*norm_src[n]) @ wcT^T, stored bf16 ----
#define GBM 64
#define GBK 64
#define ALD 72
#define BLD 72

__global__ __launch_bounds__(256) void k_gemm_mfma(
    const float* __restrict__ feat, const unsigned short* __restrict__ wcT,
    const float* __restrict__ norm_src, unsigned short* __restrict__ h2, int n)
{
  __shared__ unsigned short As[GBM][ALD];   // 64*72*2 = 9216 B
  __shared__ unsigned short Bs[OD][BLD];    // 256*72*2 = 36864 B
  const int row0 = blockIdx.x*GBM;
  const int t = threadIdx.x;
  const int wave = t >> 6, lane = t & 63;
  const int wcol0 = wave*64;
  const int l15 = lane & 15, l4 = lane >> 4;

  f32x4 acc[4][4] = {};   // [m-frag][n-frag]

  for (int k0 = 0; k0 < KD; k0 += GBK){
    #pragma unroll
    for (int i = 0; i < 4; i++){
      int flat = t + 256*i;          // 1024 float4 chunks
      int r = flat >> 4, c4 = flat & 15;
      int gr = row0 + r;
      float4 v = {0.f,0.f,0.f,0.f};
      if (gr < n){
        v = *(const float4*)(feat + (size_t)gr*KD + k0 + c4*4);
        float ns = norm_src[gr];
        v.x *= ns; v.y *= ns; v.z *= ns; v.w *= ns;
      }
      ushort4 b;
      b.x = f2bf(v.x); b.y = f2bf(v.y); b.z = f2bf(v.z); b.w = f2bf(v.w);
      *(ushort4*)(&As[r][c4*4]) = b;
    }
    #pragma unroll
    for (int i = 0; i < 8; i++){
      int flat = t + 256*i;          // 2048 16B chunks
      int r = flat >> 3, c = flat & 7;
      uint4 v = *(const uint4*)(wcT + (size_t)r*KD + k0 + c*8);
      *(uint4*)(&Bs[r][c*8]) = v;
    }
    __syncthreads();
    #pragma unroll
    for (int ks = 0; ks < 2; ks++){
      bf16x8 af[4], bfr[4];
      #pragma unroll
      for (int m = 0; m < 4; m++)
        af[m] = *(const bf16x8*)(&As[m*16 + l15][ks*32 + l4*8]);
      #pragma unroll
      for (int nn = 0; nn < 4; nn++)
        bfr[nn] = *(const bf16x8*)(&Bs[wcol0 + nn*16 + l15][ks*32 + l4*8]);
      #pragma unroll
      for (int m = 0; m < 4; m++)
        #pragma unroll
        for (int nn = 0; nn < 4; nn++)
          acc[m][nn] = __builtin_amdgcn_mfma_f32_16x16x32_bf16(af[m], bfr[nn], acc[m][nn], 0, 0, 0);
    }
    __syncthreads();
  }
  #pragma unroll
  for (int m = 0; m < 4; m++){
    #pragma unroll
    for (int r = 0; r < 4; r++){
      int row = row0 + m*16 + l4*4 + r;
      if (row < n){
        #pragma unroll
        for (int nn = 0; nn < 4; nn++){
          int col = wcol0 + nn*16 + l15;
          h2[(size_t)row*OD + col] = f2bf(acc[m][nn][r]);
        }
      }
    }
  }
}

// ---- scan kernels: exclusive prefix over indeg -> CSR offsets ----
__global__ __launch_bounds__(256) void k_scan1(const int* __restrict__ cnt,
    int* __restrict__ bsum, int n)
{
  __shared__ int wsums[4];
  int b = blockIdx.x, t = threadIdx.x;
  int base = b*1024 + t*4;
  int s = 0;
  #pragma unroll
  for (int i = 0; i < 4; i++){ int idx = base+i; if (idx < n) s += cnt[idx]; }
  #pragma unroll
  for (int d = 1; d < 64; d <<= 1) s += __shfl_xor(s, d);
  if ((t & 63) == 0) wsums[t>>6] = s;
  __syncthreads();
  if (t == 0) bsum[b] = wsums[0]+wsums[1]+wsums[2]+wsums[3];
}

__global__ void k_scan2(const int* __restrict__ bsum, int* __restrict__ boff,
                        int nb, int* __restrict__ offsets, int n)
{
  int lane = threadIdx.x;  // 64 threads, 1 block
  int running = 0;
  for (int base = 0; base < nb; base += 64){
    int v = (base+lane < nb) ? bsum[base+lane] : 0;
    int x = v;
    #pragma unroll
    for (int d = 1; d < 64; d <<= 1){ int y = __shfl_up(x, d); if (lane >= d) x += y; }
    if (base+lane < nb) boff[base+lane] = running + x - v;
    running += __shfl(x, 63);
  }
  if (lane == 0) offsets[n] = running;   // = E
}

__global__ __launch_bounds__(256) void k_scan3(const int* __restrict__ cnt,
    const int* __restrict__ boff, int* __restrict__ offsets, int n)
{
  __shared__ int wsum[4], woff[4];
  int b = blockIdx.x, t = threadIdx.x, lane = t & 63, w = t >> 6;
  int base = b*1024 + t*4;
  int c[4]; int s = 0;
  #pragma unroll
  for (int i = 0; i < 4; i++){ c[i] = (base+i < n) ? cnt[base+i] : 0; s += c[i]; }
  int x = s;
  #pragma unroll
  for (int d = 1; d < 64; d <<= 1){ int y = __shfl_up(x, d); if (lane >= d) x += y; }
  if (lane == 63) wsum[w] = x;
  __syncthreads();
  if (t == 0){ int r = 0; for (int j = 0; j < 4; j++){ woff[j] = r; r += wsum[j]; } }
  __syncthreads();
  int excl = boff[b] + woff[w] + (x - s);
  #pragma unroll
  for (int i = 0; i < 4; i++){
    if (base+i < n) offsets[base+i] = excl;
    excl += c[i];
  }
}

// ---- scatter, ATOMIC-FREE: pos = offsets[d] + cum8[shard][d] + rank (from epos) ----
__global__ __launch_bounds__(256) void k_scatter(const int* __restrict__ src,
    const int* __restrict__ dst, const unsigned* __restrict__ epos,
    const int* __restrict__ offsets, const int* __restrict__ cum8,
    int* __restrict__ esrc, int e, int n)
{
  int i0 = (blockIdx.x*256 + threadIdx.x)*4;
  if (i0 + 3 < e){
    int4 a = *(const int4*)(src + i0);
    int4 b = *(const int4*)(dst + i0);
    uint4 p = *(const uint4*)(epos + i0);
    esrc[offsets[b.x] + cum8[(int)(p.x >> 24)*n + b.x] + (int)(p.x & 0xFFFFFFu)] = a.x;
    esrc[offsets[b.y] + cum8[(int)(p.y >> 24)*n + b.y] + (int)(p.y & 0xFFFFFFu)] = a.y;
    esrc[offsets[b.z] + cum8[(int)(p.z >> 24)*n + b.z] + (int)(p.z & 0xFFFFFFu)] = a.z;
    esrc[offsets[b.w] + cum8[(int)(p.w >> 24)*n + b.w] + (int)(p.w & 0xFFFFFFu)] = a.w;
  } else {
    for (int i = i0; i < e; i++){
      int d = dst[i];
      unsigned p = epos[i];
      esrc[offsets[d] + cum8[(int)(p >> 24)*n + d] + (int)(p & 0xFFFFFFu)] = src[i];
    }
  }
}

// ---- aggregation: one wave per dst node; 2 edges per gather pass (32 lanes x 16B),
//      unrolled 4 -> 8 edges (4 KB) in flight per wave ----
__global__ __launch_bounds__(256) void k_agg(const unsigned short* __restrict__ h2,
    const int* __restrict__ offsets, const int* __restrict__ esrc,
    const int* __restrict__ indeg, const float* __restrict__ bias,
    float* __restrict__ out, int n)
{
  int node = (blockIdx.x*256 + threadIdx.x) >> 6;
  int lane = threadIdx.x & 63;
  if (node >= n) return;
  const int half = lane >> 5;        // which edge of the pair
  const int col8 = lane & 31;        // owns cols [col8*8, col8*8+8)
  int beg = offsets[node], end = offsets[node+1];

  float a0=0.f,a1=0.f,a2=0.f,a3=0.f,a4=0.f,a5=0.f,a6=0.f,a7=0.f;

  #define ACC(V) { \
    unsigned short s0 = (unsigned short)((V).x & 0xFFFFu), s1 = (unsigned short)((V).x >> 16); \
    unsigned short s2 = (unsigned short)((V).y & 0xFFFFu), s3 = (unsigned short)((V).y >> 16); \
    unsigned short s4 = (unsigned short)((V).z & 0xFFFFu), s5 = (unsigned short)((V).z >> 16); \
    unsigned short s6 = (unsigned short)((V).w & 0xFFFFu), s7 = (unsigned short)((V).w >> 16); \
    a0 += bf2f(s0); a1 += bf2f(s1); a2 += bf2f(s2); a3 += bf2f(s3); \
    a4 += bf2f(s4); a5 += bf2f(s5); a6 += bf2f(s6); a7 += bf2f(s7); }

  int i = beg;
  for (; i + 8 <= end; i += 8){
    int e0 = esrc[i     + half];
    int e1 = esrc[i + 2 + half];
    int e2 = esrc[i + 4 + half];
    int e3 = esrc[i + 6 + half];
    uint4 v0 = *(const uint4*)(h2 + (size_t)e0*OD + col8*8);
    uint4 v1 = *(const uint4*)(h2 + (size_t)e1*OD + col8*8);
    uint4 v2 = *(const uint4*)(h2 + (size_t)e2*OD + col8*8);
    uint4 v3 = *(const uint4*)(h2 + (size_t)e3*OD + col8*8);
    ACC(v0); ACC(v1); ACC(v2); ACC(v3);
  }
  for (; i + 2 <= end; i += 2){
    int e = esrc[i + half];
    uint4 v = *(const uint4*)(h2 + (size_t)e*OD + col8*8);
    ACC(v);
  }
  if (i < end && half == 0){
    int e = esrc[i];
    uint4 v = *(const uint4*)(h2 + (size_t)e*OD + col8*8);
    ACC(v);
  }
  #undef ACC

  a0 += __shfl_xor(a0, 32); a1 += __shfl_xor(a1, 32);
  a2 += __shfl_xor(a2, 32); a3 += __shfl_xor(a3, 32);
  a4 += __shfl_xor(a4, 32); a5 += __shfl_xor(a5, 32);
  a6 += __shfl_xor(a6, 32); a7 += __shfl_xor(a7, 32);

  int d = indeg[node]; if (d < 1) d = 1;
  float nd = rsqrtf((float)d);
  int c0 = col8*8 + half*4;
  const float* bz = bias + c0;
  float4 o;
  if (half == 0){
    o.x = a0*nd + bz[0]; o.y = a1*nd + bz[1];
    o.z = a2*nd + bz[2]; o.w = a3*nd + bz[3];
  } else {
    o.x = a4*nd + bz[0]; o.y = a5*nd + bz[1];
    o.z = a6*nd + bz[2]; o.w = a7*nd + bz[3];
  }
  *(float4*)(out + (size_t)node*OD + c0) = o;
}

extern "C" void kernel_launch(void* const* d_in, const int* in_sizes, int n_in,
                              void* d_out, int out_size, void* d_ws, size_t ws_size,
                              hipStream_t stream)
{
  const float* feat     = (const float*)d_in[0];
  const float* weight   = (const float*)d_in[1];
  const float* bias     = (const float*)d_in[2];
  const float* st_param = (const float*)d_in[3];
  const int*   src      = (const int*)d_in[4];
  const int*   dst      = (const int*)d_in[5];
  const int N = in_sizes[0] / KD;
  const int E = in_sizes[4];

  char* w = (char*)d_ws;
  size_t off = 0;
  auto take = [&](size_t bytes) -> char* {
    char* p = w + off;
    off = (off + bytes + 255) & ~(size_t)255;
    return p;
  };
  int* outdeg8  = (int*)take((size_t)NSH*N*4);
  int* indeg8   = (int*)take((size_t)NSH*N*4);
  char* zero_end = w + off;
  int* cum8     = (int*)take((size_t)NSH*N*4);
  unsigned* epos = (unsigned*)take((size_t)E*4);
  int* indeg    = (int*)take((size_t)N*4);
  int* offsets  = (int*)take((size_t)(N+1)*4);
  int* bsum     = (int*)take(512*4);
  int* boff     = (int*)take(512*4);
  float* norm_src = (float*)take((size_t)N*4);
  unsigned short* wcT = (unsigned short*)take((size_t)KD*OD*2);
  int* esrc     = (int*)take((size_t)E*4);
  unsigned short* h2 = (unsigned short*)take((size_t)N*OD*2);
  (void)ws_size; (void)out_size; (void)n_in;

  float* out = (float*)d_out;

  hipMemsetAsync(outdeg8, 0, (size_t)(zero_end - (char*)outdeg8), stream);

  int eb4 = (E + 1023)/1024;            // 4 edges per thread
  k_degrees<<<eb4, 256, 0, stream>>>(src, dst, outdeg8, indeg8, epos, E, N);
  k_wc<<<(KD*OD)/256, 256, 0, stream>>>(st_param, weight, wcT);
  k_red<<<(N+255)/256, 256, 0, stream>>>(outdeg8, indeg8, norm_src, indeg, cum8, N);
  k_gemm_mfma<<<(N+GBM-1)/GBM, 256, 0, stream>>>(feat, wcT, norm_src, h2, N);
  int nb = (N + 1023)/1024;
  k_scan1<<<nb, 256, 0, stream>>>(indeg, bsum, N);
  k_scan2<<<1, 64, 0, stream>>>(bsum, boff, nb, offsets, N);
  k_scan3<<<nb, 256, 0, stream>>>(indeg, boff, offsets, N);
  k_scatter<<<eb4, 256, 0, stream>>>(src, dst, epos, offsets, cum8, esrc, E, N);
  k_agg<<<(N+3)/4, 256, 0, stream>>>(h2, offsets, esrc, indeg, bias, out, N);
}

// Round 6
// 501.898 us; speedup vs baseline: 2.1842x; 1.3907x over previous
//
#include <hip/hip_runtime.h>

#define T_ 4
#define FI_ 128
#define FO_ 64
#define KD 512     // T*FI
#define OD 256     // T*FO

#define RBIN 16384 // LDS histogram bins per partition (64 KB)
#define BCH 64     // edge chunks (= rank-partial rows)

typedef __attribute__((ext_vector_type(8))) short bf16x8;
typedef __attribute__((ext_vector_type(4))) float f32x4;

static __device__ __forceinline__ float bf2f(unsigned short u){
  return __uint_as_float(((unsigned int)u) << 16);
}
static __device__ __forceinline__ unsigned short f2bf(float f){
  unsigned int u = __float_as_uint(f);
  u += 0x7FFFu + ((u >> 16) & 1u);
  return (unsigned short)(u >> 16);
}

// ---- outdeg histogram: LDS bins, node-partitioned; NO device atomics ----
__global__ __launch_bounds__(256) void k_hist_out(const int* __restrict__ src,
    unsigned short* __restrict__ cnt_out, int e, int n, int C)
{
  __shared__ int h[RBIN];
  for (int j = threadIdx.x; j < RBIN; j += 256) h[j] = 0;
  __syncthreads();
  const int lo  = blockIdx.y * RBIN;
  const int beg = blockIdx.x * C;
  const int end = min(beg + C, e);
  for (int i = beg + (int)threadIdx.x*4; i < end; i += 1024){
    if (i + 3 < end){
      int4 s4 = *(const int4*)(src + i);
      unsigned x0 = (unsigned)(s4.x - lo), x1 = (unsigned)(s4.y - lo);
      unsigned x2 = (unsigned)(s4.z - lo), x3 = (unsigned)(s4.w - lo);
      if (x0 < RBIN) atomicAdd(&h[x0], 1);
      if (x1 < RBIN) atomicAdd(&h[x1], 1);
      if (x2 < RBIN) atomicAdd(&h[x2], 1);
      if (x3 < RBIN) atomicAdd(&h[x3], 1);
    } else {
      for (int k = i; k < end; k++){
        unsigned x = (unsigned)(src[k] - lo);
        if (x < RBIN) atomicAdd(&h[x], 1);
      }
    }
  }
  __syncthreads();
  const int hi = min(RBIN, n - lo);
  unsigned short* row = cnt_out + (size_t)blockIdx.x * n + lo;
  for (int j = threadIdx.x; j < hi; j += 256) row[j] = (unsigned short)h[j];
}

// ---- indeg histogram + per-edge rank (LDS fetch_add); NO device atomics ----
__global__ __launch_bounds__(256) void k_hist_in(const int* __restrict__ dst,
    unsigned short* __restrict__ cnt_in, unsigned short* __restrict__ epos,
    int e, int n, int C)
{
  __shared__ int h[RBIN];
  for (int j = threadIdx.x; j < RBIN; j += 256) h[j] = 0;
  __syncthreads();
  const int lo  = blockIdx.y * RBIN;
  const int beg = blockIdx.x * C;
  const int end = min(beg + C, e);
  for (int i = beg + (int)threadIdx.x*4; i < end; i += 1024){
    if (i + 3 < end){
      int4 d4 = *(const int4*)(dst + i);
      unsigned x0 = (unsigned)(d4.x - lo), x1 = (unsigned)(d4.y - lo);
      unsigned x2 = (unsigned)(d4.z - lo), x3 = (unsigned)(d4.w - lo);
      if (x0 < RBIN) epos[i  ] = (unsigned short)atomicAdd(&h[x0], 1);
      if (x1 < RBIN) epos[i+1] = (unsigned short)atomicAdd(&h[x1], 1);
      if (x2 < RBIN) epos[i+2] = (unsigned short)atomicAdd(&h[x2], 1);
      if (x3 < RBIN) epos[i+3] = (unsigned short)atomicAdd(&h[x3], 1);
    } else {
      for (int k = i; k < end; k++){
        unsigned x = (unsigned)(dst[k] - lo);
        if (x < RBIN) epos[k] = (unsigned short)atomicAdd(&h[x], 1);
      }
    }
  }
  __syncthreads();
  const int hi = min(RBIN, n - lo);
  unsigned short* row = cnt_in + (size_t)blockIdx.x * n + lo;
  for (int j = threadIdx.x; j < hi; j += 256) row[j] = (unsigned short)h[j];
}

// ---- reduce chunk-partials -> norm_src, indeg, per-chunk exclusive cumB ----
__global__ __launch_bounds__(256) void k_red(const unsigned short* __restrict__ cnt_out,
    const unsigned short* __restrict__ cnt_in, float* __restrict__ norm_src,
    int* __restrict__ indeg, int* __restrict__ cumB, int n)
{
  int i = blockIdx.x*256 + threadIdx.x;
  if (i >= n) return;
  int od = 0;
  #pragma unroll 8
  for (int b = 0; b < BCH; b++) od += (int)cnt_out[(size_t)b*n + i];
  if (od < 1) od = 1;
  norm_src[i] = rsqrtf((float)od);
  int c = 0;
  #pragma unroll 8
  for (int b = 0; b < BCH; b++){
    cumB[(size_t)b*n + i] = c;
    c += (int)cnt_in[(size_t)b*n + i];
  }
  indeg[i] = c;
}

// ---- combined weight, bf16 TRANSPOSED: wcT[(t*FO+o)][s*FI+f] = st_m[t][s]*weight[t][f][o] ----
__global__ __launch_bounds__(256) void k_wc(const float* __restrict__ st_param,
    const float* __restrict__ weight, unsigned short* __restrict__ wcT)
{
  int idx = blockIdx.x*256 + threadIdx.x;   // 256*512 total, exact grid
  int c = idx >> 9, r = idx & 511;          // c = out col (t,o), r = in row (s,f)
  int s = r >> 7, f = r & 127, t = c >> 6, o = c & 63;
  float p0 = st_param[t*4+0], p1 = st_param[t*4+1], p2 = st_param[t*4+2], p3 = st_param[t*4+3];
  float m = fmaxf(fmaxf(p0,p1), fmaxf(p2,p3));
  float e0 = expf(p0-m), e1 = expf(p1-m), e2 = expf(p2-m), e3 = expf(p3-m);
  float sum = e0+e1+e2+e3;
  float sel = (s==0)?e0:((s==1)?e1:((s==2)?e2:e3));
  wcT[idx] = f2bf((sel/sum) * weight[(t*FI_+f)*FO_ + o]);
}

// ---- MFMA bf16 GEMM: h2[n][256] = bf16(feat[n]*norm_src[n]) @ wcT^T, stored bf16 ----
#define GBM 64
#define GBK 64
#define ALD 72
#define BLD 72

__global__ __launch_bounds__(256) void k_gemm_mfma(
    const float* __restrict__ feat, const unsigned short* __restrict__ wcT,
    const float* __restrict__ norm_src, unsigned short* __restrict__ h2, int n)
{
  __shared__ unsigned short As[GBM][ALD];   // 64*72*2 = 9216 B
  __shared__ unsigned short Bs[OD][BLD];    // 256*72*2 = 36864 B
  const int row0 = blockIdx.x*GBM;
  const int t = threadIdx.x;
  const int wave = t >> 6, lane = t & 63;
  const int wcol0 = wave*64;
  const int l15 = lane & 15, l4 = lane >> 4;

  f32x4 acc[4][4] = {};   // [m-frag][n-frag]

  for (int k0 = 0; k0 < KD; k0 += GBK){
    #pragma unroll
    for (int i = 0; i < 4; i++){
      int flat = t + 256*i;          // 1024 float4 chunks
      int r = flat >> 4, c4 = flat & 15;
      int gr = row0 + r;
      float4 v = {0.f,0.f,0.f,0.f};
      if (gr < n){
        v = *(const float4*)(feat + (size_t)gr*KD + k0 + c4*4);
        float ns = norm_src[gr];
        v.x *= ns; v.y *= ns; v.z *= ns; v.w *= ns;
      }
      ushort4 b;
      b.x = f2bf(v.x); b.y = f2bf(v.y); b.z = f2bf(v.z); b.w = f2bf(v.w);
      *(ushort4*)(&As[r][c4*4]) = b;
    }
    #pragma unroll
    for (int i = 0; i < 8; i++){
      int flat = t + 256*i;          // 2048 16B chunks
      int r = flat >> 3, c = flat & 7;
      uint4 v = *(const uint4*)(wcT + (size_t)r*KD + k0 + c*8);
      *(uint4*)(&Bs[r][c*8]) = v;
    }
    __syncthreads();
    #pragma unroll
    for (int ks = 0; ks < 2; ks++){
      bf16x8 af[4], bfr[4];
      #pragma unroll
      for (int m = 0; m < 4; m++)
        af[m] = *(const bf16x8*)(&As[m*16 + l15][ks*32 + l4*8]);
      #pragma unroll
      for (int nn = 0; nn < 4; nn++)
        bfr[nn] = *(const bf16x8*)(&Bs[wcol0 + nn*16 + l15][ks*32 + l4*8]);
      #pragma unroll
      for (int m = 0; m < 4; m++)
        #pragma unroll
        for (int nn = 0; nn < 4; nn++)
          acc[m][nn] = __builtin_amdgcn_mfma_f32_16x16x32_bf16(af[m], bfr[nn], acc[m][nn], 0, 0, 0);
    }
    __syncthreads();
  }
  #pragma unroll
  for (int m = 0; m < 4; m++){
    #pragma unroll
    for (int r = 0; r < 4; r++){
      int row = row0 + m*16 + l4*4 + r;
      if (row < n){
        #pragma unroll
        for (int nn = 0; nn < 4; nn++){
          int col = wcol0 + nn*16 + l15;
          h2[(size_t)row*OD + col] = f2bf(acc[m][nn][r]);
        }
      }
    }
  }
}

// ---- scan kernels: exclusive prefix over indeg -> CSR offsets ----
__global__ __launch_bounds__(256) void k_scan1(const int* __restrict__ cnt,
    int* __restrict__ bsum, int n)
{
  __shared__ int wsums[4];
  int b = blockIdx.x, t = threadIdx.x;
  int base = b*1024 + t*4;
  int s = 0;
  #pragma unroll
  for (int i = 0; i < 4; i++){ int idx = base+i; if (idx < n) s += cnt[idx]; }
  #pragma unroll
  for (int d = 1; d < 64; d <<= 1) s += __shfl_xor(s, d);
  if ((t & 63) == 0) wsums[t>>6] = s;
  __syncthreads();
  if (t == 0) bsum[b] = wsums[0]+wsums[1]+wsums[2]+wsums[3];
}

__global__ void k_scan2(const int* __restrict__ bsum, int* __restrict__ boff,
                        int nb, int* __restrict__ offsets, int n)
{
  int lane = threadIdx.x;  // 64 threads, 1 block
  int running = 0;
  for (int base = 0; base < nb; base += 64){
    int v = (base+lane < nb) ? bsum[base+lane] : 0;
    int x = v;
    #pragma unroll
    for (int d = 1; d < 64; d <<= 1){ int y = __shfl_up(x, d); if (lane >= d) x += y; }
    if (base+lane < nb) boff[base+lane] = running + x - v;
    running += __shfl(x, 63);
  }
  if (lane == 0) offsets[n] = running;   // = E
}

__global__ __launch_bounds__(256) void k_scan3(const int* __restrict__ cnt,
    const int* __restrict__ boff, int* __restrict__ offsets, int n)
{
  __shared__ int wsum[4], woff[4];
  int b = blockIdx.x, t = threadIdx.x, lane = t & 63, w = t >> 6;
  int base = b*1024 + t*4;
  int c[4]; int s = 0;
  #pragma unroll
  for (int i = 0; i < 4; i++){ c[i] = (base+i < n) ? cnt[base+i] : 0; s += c[i]; }
  int x = s;
  #pragma unroll
  for (int d = 1; d < 64; d <<= 1){ int y = __shfl_up(x, d); if (lane >= d) x += y; }
  if (lane == 63) wsum[w] = x;
  __syncthreads();
  if (t == 0){ int r = 0; for (int j = 0; j < 4; j++){ woff[j] = r; r += wsum[j]; } }
  __syncthreads();
  int excl = boff[b] + woff[w] + (x - s);
  #pragma unroll
  for (int i = 0; i < 4; i++){
    if (base+i < n) offsets[base+i] = excl;
    excl += c[i];
  }
}

// ---- scatter, ATOMIC-FREE: pos = offsets[d] + cumB[chunk][d] + rank ----
__global__ __launch_bounds__(256) void k_scatter(const int* __restrict__ src,
    const int* __restrict__ dst, const unsigned short* __restrict__ epos,
    const int* __restrict__ offsets, const int* __restrict__ cumB,
    int* __restrict__ esrc, int e, int n, int C)
{
  int i0 = (blockIdx.x*256 + threadIdx.x)*4;
  if (i0 + 3 < e){
    int b = i0 / C;              // C % 4 == 0 -> all 4 edges in same chunk
    const int* cb = cumB + (size_t)b*n;
    int4 a = *(const int4*)(src + i0);
    int4 d4 = *(const int4*)(dst + i0);
    ushort4 p = *(const ushort4*)(epos + i0);
    esrc[offsets[d4.x] + cb[d4.x] + (int)p.x] = a.x;
    esrc[offsets[d4.y] + cb[d4.y] + (int)p.y] = a.y;
    esrc[offsets[d4.z] + cb[d4.z] + (int)p.z] = a.z;
    esrc[offsets[d4.w] + cb[d4.w] + (int)p.w] = a.w;
  } else {
    for (int i = i0; i < e; i++){
      int d = dst[i];
      int b = i / C;
      esrc[offsets[d] + cumB[(size_t)b*n + d] + (int)epos[i]] = src[i];
    }
  }
}

// ---- aggregation: one wave per dst node; 2 edges per gather pass (32 lanes x 16B),
//      unrolled 4 -> 8 edges (4 KB) in flight per wave ----
__global__ __launch_bounds__(256) void k_agg(const unsigned short* __restrict__ h2,
    const int* __restrict__ offsets, const int* __restrict__ esrc,
    const int* __restrict__ indeg, const float* __restrict__ bias,
    float* __restrict__ out, int n)
{
  int node = (blockIdx.x*256 + threadIdx.x) >> 6;
  int lane = threadIdx.x & 63;
  if (node >= n) return;
  const int half = lane >> 5;        // which edge of the pair
  const int col8 = lane & 31;        // owns cols [col8*8, col8*8+8)
  int beg = offsets[node], end = offsets[node+1];

  float a0=0.f,a1=0.f,a2=0.f,a3=0.f,a4=0.f,a5=0.f,a6=0.f,a7=0.f;

  #define ACC(V) { \
    unsigned short s0 = (unsigned short)((V).x & 0xFFFFu), s1 = (unsigned short)((V).x >> 16); \
    unsigned short s2 = (unsigned short)((V).y & 0xFFFFu), s3 = (unsigned short)((V).y >> 16); \
    unsigned short s4 = (unsigned short)((V).z & 0xFFFFu), s5 = (unsigned short)((V).z >> 16); \
    unsigned short s6 = (unsigned short)((V).w & 0xFFFFu), s7 = (unsigned short)((V).w >> 16); \
    a0 += bf2f(s0); a1 += bf2f(s1); a2 += bf2f(s2); a3 += bf2f(s3); \
    a4 += bf2f(s4); a5 += bf2f(s5); a6 += bf2f(s6); a7 += bf2f(s7); }

  int i = beg;
  for (; i + 8 <= end; i += 8){
    int e0 = esrc[i     + half];
    int e1 = esrc[i + 2 + half];
    int e2 = esrc[i + 4 + half];
    int e3 = esrc[i + 6 + half];
    uint4 v0 = *(const uint4*)(h2 + (size_t)e0*OD + col8*8);
    uint4 v1 = *(const uint4*)(h2 + (size_t)e1*OD + col8*8);
    uint4 v2 = *(const uint4*)(h2 + (size_t)e2*OD + col8*8);
    uint4 v3 = *(const uint4*)(h2 + (size_t)e3*OD + col8*8);
    ACC(v0); ACC(v1); ACC(v2); ACC(v3);
  }
  for (; i + 2 <= end; i += 2){
    int e = esrc[i + half];
    uint4 v = *(const uint4*)(h2 + (size_t)e*OD + col8*8);
    ACC(v);
  }
  if (i < end && half == 0){
    int e = esrc[i];
    uint4 v = *(const uint4*)(h2 + (size_t)e*OD + col8*8);
    ACC(v);
  }
  #undef ACC

  a0 += __shfl_xor(a0, 32); a1 += __shfl_xor(a1, 32);
  a2 += __shfl_xor(a2, 32); a3 += __shfl_xor(a3, 32);
  a4 += __shfl_xor(a4, 32); a5 += __shfl_xor(a5, 32);
  a6 += __shfl_xor(a6, 32); a7 += __shfl_xor(a7, 32);

  int d = indeg[node]; if (d < 1) d = 1;
  float nd = rsqrtf((float)d);
  int c0 = col8*8 + half*4;
  const float* bz = bias + c0;
  float4 o;
  if (half == 0){
    o.x = a0*nd + bz[0]; o.y = a1*nd + bz[1];
    o.z = a2*nd + bz[2]; o.w = a3*nd + bz[3];
  } else {
    o.x = a4*nd + bz[0]; o.y = a5*nd + bz[1];
    o.z = a6*nd + bz[2]; o.w = a7*nd + bz[3];
  }
  *(float4*)(out + (size_t)node*OD + c0) = o;
}

extern "C" void kernel_launch(void* const* d_in, const int* in_sizes, int n_in,
                              void* d_out, int out_size, void* d_ws, size_t ws_size,
                              hipStream_t stream)
{
  const float* feat     = (const float*)d_in[0];
  const float* weight   = (const float*)d_in[1];
  const float* bias     = (const float*)d_in[2];
  const float* st_param = (const float*)d_in[3];
  const int*   src      = (const int*)d_in[4];
  const int*   dst      = (const int*)d_in[5];
  const int N = in_sizes[0] / KD;
  const int E = in_sizes[4];

  char* w = (char*)d_ws;
  size_t off = 0;
  auto take = [&](size_t bytes) -> char* {
    char* p = w + off;
    off = (off + bytes + 255) & ~(size_t)255;
    return p;
  };
  unsigned short* cnt_out = (unsigned short*)take((size_t)BCH*N*2);
  unsigned short* cnt_in  = (unsigned short*)take((size_t)BCH*N*2);
  int* cumB     = (int*)take((size_t)BCH*N*4);
  unsigned short* epos = (unsigned short*)take((size_t)E*2);
  int* indeg    = (int*)take((size_t)N*4);
  int* offsets  = (int*)take((size_t)(N+1)*4);
  int* bsum     = (int*)take(512*4);
  int* boff     = (int*)take(512*4);
  float* norm_src = (float*)take((size_t)N*4);
  unsigned short* wcT = (unsigned short*)take((size_t)KD*OD*2);
  int* esrc     = (int*)take((size_t)E*4);
  unsigned short* h2 = (unsigned short*)take((size_t)N*OD*2);
  (void)ws_size; (void)out_size; (void)n_in;

  float* out = (float*)d_out;

  // chunk size: multiple of 1024, BCH*C >= E
  int C = (((E + BCH - 1)/BCH) + 1023) & ~1023;
  int nparts = (N + RBIN - 1)/RBIN;
  dim3 gh(BCH, nparts);
  k_hist_out<<<gh, 256, 0, stream>>>(src, cnt_out, E, N, C);
  k_hist_in <<<gh, 256, 0, stream>>>(dst, cnt_in, epos, E, N, C);
  k_wc<<<(KD*OD)/256, 256, 0, stream>>>(st_param, weight, wcT);
  k_red<<<(N+255)/256, 256, 0, stream>>>(cnt_out, cnt_in, norm_src, indeg, cumB, N);
  k_gemm_mfma<<<(N+GBM-1)/GBM, 256, 0, stream>>>(feat, wcT, norm_src, h2, N);
  int nb = (N + 1023)/1024;
  k_scan1<<<nb, 256, 0, stream>>>(indeg, bsum, N);
  k_scan2<<<1, 64, 0, stream>>>(bsum, boff, nb, offsets, N);
  k_scan3<<<nb, 256, 0, stream>>>(indeg, boff, offsets, N);
  int eb4 = (E + 1023)/1024;
  k_scatter<<<eb4, 256, 0, stream>>>(src, dst, epos, offsets, cumB, esrc, E, N, C);
  k_agg<<<(N+3)/4, 256, 0, stream>>>(h2, offsets, esrc, indeg, bias, out, N);
}

// Round 7
// 476.002 us; speedup vs baseline: 2.3030x; 1.0544x over previous
//
#include <hip/hip_runtime.h>

#define T_ 4
#define FI_ 128
#define FO_ 64
#define KD 512     // T*FI
#define OD 256     // T*FO

#define RBIN 16384 // LDS histogram bins per partition (64 KB)
#define BCH 64     // edge chunks (= rank-partial rows)

typedef __attribute__((ext_vector_type(8))) short bf16x8;
typedef __attribute__((ext_vector_type(4))) float f32x4;

static __device__ __forceinline__ float bf2f(unsigned short u){
  return __uint_as_float(((unsigned int)u) << 16);
}
static __device__ __forceinline__ unsigned short f2bf(float f){
  unsigned int u = __float_as_uint(f);
  u += 0x7FFFu + ((u >> 16) & 1u);
  return (unsigned short)(u >> 16);
}

// ---- outdeg histogram: LDS bins, node-partitioned; NO device atomics ----
__global__ __launch_bounds__(256) void k_hist_out(const int* __restrict__ src,
    unsigned short* __restrict__ cnt_out, int e, int n, int C)
{
  __shared__ int h[RBIN];
  for (int j = threadIdx.x; j < RBIN; j += 256) h[j] = 0;
  __syncthreads();
  const int lo  = blockIdx.y * RBIN;
  const int beg = blockIdx.x * C;
  const int end = min(beg + C, e);
  for (int i = beg + (int)threadIdx.x*4; i < end; i += 1024){
    if (i + 3 < end){
      int4 s4 = *(const int4*)(src + i);
      unsigned x0 = (unsigned)(s4.x - lo), x1 = (unsigned)(s4.y - lo);
      unsigned x2 = (unsigned)(s4.z - lo), x3 = (unsigned)(s4.w - lo);
      if (x0 < RBIN) atomicAdd(&h[x0], 1);
      if (x1 < RBIN) atomicAdd(&h[x1], 1);
      if (x2 < RBIN) atomicAdd(&h[x2], 1);
      if (x3 < RBIN) atomicAdd(&h[x3], 1);
    } else {
      for (int k = i; k < end; k++){
        unsigned x = (unsigned)(src[k] - lo);
        if (x < RBIN) atomicAdd(&h[x], 1);
      }
    }
  }
  __syncthreads();
  const int hi = min(RBIN, n - lo);
  unsigned short* row = cnt_out + (size_t)blockIdx.x * n + lo;
  for (int j = threadIdx.x; j < hi; j += 256) row[j] = (unsigned short)h[j];
}

// ---- indeg histogram + per-edge rank (LDS fetch_add); NO device atomics ----
__global__ __launch_bounds__(256) void k_hist_in(const int* __restrict__ dst,
    unsigned short* __restrict__ cnt_in, unsigned short* __restrict__ epos,
    int e, int n, int C)
{
  __shared__ int h[RBIN];
  for (int j = threadIdx.x; j < RBIN; j += 256) h[j] = 0;
  __syncthreads();
  const int lo  = blockIdx.y * RBIN;
  const int beg = blockIdx.x * C;
  const int end = min(beg + C, e);
  for (int i = beg + (int)threadIdx.x*4; i < end; i += 1024){
    if (i + 3 < end){
      int4 d4 = *(const int4*)(dst + i);
      unsigned x0 = (unsigned)(d4.x - lo), x1 = (unsigned)(d4.y - lo);
      unsigned x2 = (unsigned)(d4.z - lo), x3 = (unsigned)(d4.w - lo);
      if (x0 < RBIN) epos[i  ] = (unsigned short)atomicAdd(&h[x0], 1);
      if (x1 < RBIN) epos[i+1] = (unsigned short)atomicAdd(&h[x1], 1);
      if (x2 < RBIN) epos[i+2] = (unsigned short)atomicAdd(&h[x2], 1);
      if (x3 < RBIN) epos[i+3] = (unsigned short)atomicAdd(&h[x3], 1);
    } else {
      for (int k = i; k < end; k++){
        unsigned x = (unsigned)(dst[k] - lo);
        if (x < RBIN) epos[k] = (unsigned short)atomicAdd(&h[x], 1);
      }
    }
  }
  __syncthreads();
  const int hi = min(RBIN, n - lo);
  unsigned short* row = cnt_in + (size_t)blockIdx.x * n + lo;
  for (int j = threadIdx.x; j < hi; j += 256) row[j] = (unsigned short)h[j];
}

// ---- reduce chunk-partials -> norm_src, indeg, per-chunk exclusive cumB ----
__global__ __launch_bounds__(256) void k_red(const unsigned short* __restrict__ cnt_out,
    const unsigned short* __restrict__ cnt_in, float* __restrict__ norm_src,
    int* __restrict__ indeg, int* __restrict__ cumB, int n)
{
  int i = blockIdx.x*256 + threadIdx.x;
  if (i >= n) return;
  int od = 0;
  #pragma unroll 8
  for (int b = 0; b < BCH; b++) od += (int)cnt_out[(size_t)b*n + i];
  if (od < 1) od = 1;
  norm_src[i] = rsqrtf((float)od);
  int c = 0;
  #pragma unroll 8
  for (int b = 0; b < BCH; b++){
    cumB[(size_t)b*n + i] = c;
    c += (int)cnt_in[(size_t)b*n + i];
  }
  indeg[i] = c;
}

// ---- combined weight, bf16 TRANSPOSED: wcT[(t*FO+o)][s*FI+f] = st_m[t][s]*weight[t][f][o] ----
__global__ __launch_bounds__(256) void k_wc(const float* __restrict__ st_param,
    const float* __restrict__ weight, unsigned short* __restrict__ wcT)
{
  int idx = blockIdx.x*256 + threadIdx.x;   // 256*512 total, exact grid
  int c = idx >> 9, r = idx & 511;          // c = out col (t,o), r = in row (s,f)
  int s = r >> 7, f = r & 127, t = c >> 6, o = c & 63;
  float p0 = st_param[t*4+0], p1 = st_param[t*4+1], p2 = st_param[t*4+2], p3 = st_param[t*4+3];
  float m = fmaxf(fmaxf(p0,p1), fmaxf(p2,p3));
  float e0 = expf(p0-m), e1 = expf(p1-m), e2 = expf(p2-m), e3 = expf(p3-m);
  float sum = e0+e1+e2+e3;
  float sel = (s==0)?e0:((s==1)?e1:((s==2)?e2:e3));
  wcT[idx] = f2bf((sel/sum) * weight[(t*FI_+f)*FO_ + o]);
}

// ---- MFMA bf16 GEMM, 128x256 tile, 8 waves; norm applied in EPILOGUE ----
#define GBM 128
#define GBK 64
#define ALD 72
#define BLD 72

__global__ __launch_bounds__(512) void k_gemm_mfma(
    const float* __restrict__ feat, const unsigned short* __restrict__ wcT,
    const float* __restrict__ norm_src, unsigned short* __restrict__ h2, int n)
{
  __shared__ unsigned short As[GBM][ALD];   // 128*72*2 = 18432 B
  __shared__ unsigned short Bs[OD][BLD];    // 256*72*2 = 36864 B
  const int row0 = blockIdx.x*GBM;
  const int t = threadIdx.x;
  const int wave = t >> 6, lane = t & 63;
  const int wr = (wave >> 2)*64;      // wave row quadrant (0,64)
  const int wc = (wave & 3)*64;       // wave col quadrant (0..192)
  const int l15 = lane & 15, l4 = lane >> 4;

  f32x4 acc[4][4] = {};   // [m-frag][n-frag]

  for (int k0 = 0; k0 < KD; k0 += GBK){
    // A: 128 rows x 64 fp32 -> bf16 LDS (no scaling here)
    #pragma unroll
    for (int i = 0; i < 4; i++){
      int flat = t + 512*i;          // 2048 float4 chunks
      int r = flat >> 4, c4 = flat & 15;
      int gr = row0 + r;
      float4 v = {0.f,0.f,0.f,0.f};
      if (gr < n) v = *(const float4*)(feat + (size_t)gr*KD + k0 + c4*4);
      ushort4 b;
      b.x = f2bf(v.x); b.y = f2bf(v.y); b.z = f2bf(v.z); b.w = f2bf(v.w);
      *(ushort4*)(&As[r][c4*4]) = b;
    }
    // B: 256 cols x 64 k bf16
    #pragma unroll
    for (int i = 0; i < 4; i++){
      int flat = t + 512*i;          // 2048 16B chunks
      int r = flat >> 3, c = flat & 7;
      uint4 v = *(const uint4*)(wcT + (size_t)r*KD + k0 + c*8);
      *(uint4*)(&Bs[r][c*8]) = v;
    }
    __syncthreads();
    #pragma unroll
    for (int ks = 0; ks < 2; ks++){
      bf16x8 af[4], bfr[4];
      #pragma unroll
      for (int m = 0; m < 4; m++)
        af[m] = *(const bf16x8*)(&As[wr + m*16 + l15][ks*32 + l4*8]);
      #pragma unroll
      for (int nn = 0; nn < 4; nn++)
        bfr[nn] = *(const bf16x8*)(&Bs[wc + nn*16 + l15][ks*32 + l4*8]);
      #pragma unroll
      for (int m = 0; m < 4; m++)
        #pragma unroll
        for (int nn = 0; nn < 4; nn++)
          acc[m][nn] = __builtin_amdgcn_mfma_f32_16x16x32_bf16(af[m], bfr[nn], acc[m][nn], 0, 0, 0);
    }
    __syncthreads();
  }
  // epilogue: scale by norm_src[row], C/D layout col=lane&15, row=(lane>>4)*4+reg
  #pragma unroll
  for (int m = 0; m < 4; m++){
    #pragma unroll
    for (int r = 0; r < 4; r++){
      int row = row0 + wr + m*16 + l4*4 + r;
      if (row < n){
        float ns = norm_src[row];
        #pragma unroll
        for (int nn = 0; nn < 4; nn++){
          int col = wc + nn*16 + l15;
          h2[(size_t)row*OD + col] = f2bf(acc[m][nn][r] * ns);
        }
      }
    }
  }
}

// ---- scan kernels: exclusive prefix over indeg -> CSR offsets ----
__global__ __launch_bounds__(256) void k_scan1(const int* __restrict__ cnt,
    int* __restrict__ bsum, int n)
{
  __shared__ int wsums[4];
  int b = blockIdx.x, t = threadIdx.x;
  int base = b*1024 + t*4;
  int s = 0;
  #pragma unroll
  for (int i = 0; i < 4; i++){ int idx = base+i; if (idx < n) s += cnt[idx]; }
  #pragma unroll
  for (int d = 1; d < 64; d <<= 1) s += __shfl_xor(s, d);
  if ((t & 63) == 0) wsums[t>>6] = s;
  __syncthreads();
  if (t == 0) bsum[b] = wsums[0]+wsums[1]+wsums[2]+wsums[3];
}

__global__ void k_scan2(const int* __restrict__ bsum, int* __restrict__ boff,
                        int nb, int* __restrict__ offsets, int n)
{
  int lane = threadIdx.x;  // 64 threads, 1 block
  int running = 0;
  for (int base = 0; base < nb; base += 64){
    int v = (base+lane < nb) ? bsum[base+lane] : 0;
    int x = v;
    #pragma unroll
    for (int d = 1; d < 64; d <<= 1){ int y = __shfl_up(x, d); if (lane >= d) x += y; }
    if (base+lane < nb) boff[base+lane] = running + x - v;
    running += __shfl(x, 63);
  }
  if (lane == 0) offsets[n] = running;   // = E
}

__global__ __launch_bounds__(256) void k_scan3(const int* __restrict__ cnt,
    const int* __restrict__ boff, int* __restrict__ offsets, int n)
{
  __shared__ int wsum[4], woff[4];
  int b = blockIdx.x, t = threadIdx.x, lane = t & 63, w = t >> 6;
  int base = b*1024 + t*4;
  int c[4]; int s = 0;
  #pragma unroll
  for (int i = 0; i < 4; i++){ c[i] = (base+i < n) ? cnt[base+i] : 0; s += c[i]; }
  int x = s;
  #pragma unroll
  for (int d = 1; d < 64; d <<= 1){ int y = __shfl_up(x, d); if (lane >= d) x += y; }
  if (lane == 63) wsum[w] = x;
  __syncthreads();
  if (t == 0){ int r = 0; for (int j = 0; j < 4; j++){ woff[j] = r; r += wsum[j]; } }
  __syncthreads();
  int excl = boff[b] + woff[w] + (x - s);
  #pragma unroll
  for (int i = 0; i < 4; i++){
    if (base+i < n) offsets[base+i] = excl;
    excl += c[i];
  }
}

// ---- scatter, ATOMIC-FREE: pos = offsets[d] + cumB[chunk][d] + rank ----
__global__ __launch_bounds__(256) void k_scatter(const int* __restrict__ src,
    const int* __restrict__ dst, const unsigned short* __restrict__ epos,
    const int* __restrict__ offsets, const int* __restrict__ cumB,
    int* __restrict__ esrc, int e, int n, int C)
{
  int i0 = (blockIdx.x*256 + threadIdx.x)*4;
  if (i0 + 3 < e){
    int b = i0 / C;              // C % 4 == 0 -> all 4 edges in same chunk
    const int* cb = cumB + (size_t)b*n;
    int4 a = *(const int4*)(src + i0);
    int4 d4 = *(const int4*)(dst + i0);
    ushort4 p = *(const ushort4*)(epos + i0);
    esrc[offsets[d4.x] + cb[d4.x] + (int)p.x] = a.x;
    esrc[offsets[d4.y] + cb[d4.y] + (int)p.y] = a.y;
    esrc[offsets[d4.z] + cb[d4.z] + (int)p.z] = a.z;
    esrc[offsets[d4.w] + cb[d4.w] + (int)p.w] = a.w;
  } else {
    for (int i = i0; i < e; i++){
      int d = dst[i];
      int b = i / C;
      esrc[offsets[d] + cumB[(size_t)b*n + d] + (int)epos[i]] = src[i];
    }
  }
}

// ---- aggregation v3: one wave per dst node; 2 edges per gather (32 lanes x 16B),
//      16 edges (8 KB) in flight per wave ----
__global__ __launch_bounds__(256) void k_agg(const unsigned short* __restrict__ h2,
    const int* __restrict__ offsets, const int* __restrict__ esrc,
    const int* __restrict__ indeg, const float* __restrict__ bias,
    float* __restrict__ out, int n)
{
  int node = (blockIdx.x*256 + threadIdx.x) >> 6;
  int lane = threadIdx.x & 63;
  if (node >= n) return;
  const int half = lane >> 5;        // which edge of the pair
  const int col8 = lane & 31;        // owns cols [col8*8, col8*8+8)
  int beg = offsets[node], end = offsets[node+1];

  float a0=0.f,a1=0.f,a2=0.f,a3=0.f,a4=0.f,a5=0.f,a6=0.f,a7=0.f;

  #define ACC(V) { \
    unsigned short s0 = (unsigned short)((V).x & 0xFFFFu), s1 = (unsigned short)((V).x >> 16); \
    unsigned short s2 = (unsigned short)((V).y & 0xFFFFu), s3 = (unsigned short)((V).y >> 16); \
    unsigned short s4 = (unsigned short)((V).z & 0xFFFFu), s5 = (unsigned short)((V).z >> 16); \
    unsigned short s6 = (unsigned short)((V).w & 0xFFFFu), s7 = (unsigned short)((V).w >> 16); \
    a0 += bf2f(s0); a1 += bf2f(s1); a2 += bf2f(s2); a3 += bf2f(s3); \
    a4 += bf2f(s4); a5 += bf2f(s5); a6 += bf2f(s6); a7 += bf2f(s7); }

  int i = beg;
  for (; i + 16 <= end; i += 16){
    int e0 = esrc[i      + half];
    int e1 = esrc[i +  2 + half];
    int e2 = esrc[i +  4 + half];
    int e3 = esrc[i +  6 + half];
    int e4 = esrc[i +  8 + half];
    int e5 = esrc[i + 10 + half];
    int e6 = esrc[i + 12 + half];
    int e7 = esrc[i + 14 + half];
    uint4 v0 = *(const uint4*)(h2 + (size_t)e0*OD + col8*8);
    uint4 v1 = *(const uint4*)(h2 + (size_t)e1*OD + col8*8);
    uint4 v2 = *(const uint4*)(h2 + (size_t)e2*OD + col8*8);
    uint4 v3 = *(const uint4*)(h2 + (size_t)e3*OD + col8*8);
    uint4 v4 = *(const uint4*)(h2 + (size_t)e4*OD + col8*8);
    uint4 v5 = *(const uint4*)(h2 + (size_t)e5*OD + col8*8);
    uint4 v6 = *(const uint4*)(h2 + (size_t)e6*OD + col8*8);
    uint4 v7 = *(const uint4*)(h2 + (size_t)e7*OD + col8*8);
    ACC(v0); ACC(v1); ACC(v2); ACC(v3);
    ACC(v4); ACC(v5); ACC(v6); ACC(v7);
  }
  for (; i + 2 <= end; i += 2){
    int e = esrc[i + half];
    uint4 v = *(const uint4*)(h2 + (size_t)e*OD + col8*8);
    ACC(v);
  }
  if (i < end && half == 0){
    int e = esrc[i];
    uint4 v = *(const uint4*)(h2 + (size_t)e*OD + col8*8);
    ACC(v);
  }
  #undef ACC

  a0 += __shfl_xor(a0, 32); a1 += __shfl_xor(a1, 32);
  a2 += __shfl_xor(a2, 32); a3 += __shfl_xor(a3, 32);
  a4 += __shfl_xor(a4, 32); a5 += __shfl_xor(a5, 32);
  a6 += __shfl_xor(a6, 32); a7 += __shfl_xor(a7, 32);

  int d = indeg[node]; if (d < 1) d = 1;
  float nd = rsqrtf((float)d);
  int c0 = col8*8 + half*4;
  const float* bz = bias + c0;
  float4 o;
  if (half == 0){
    o.x = a0*nd + bz[0]; o.y = a1*nd + bz[1];
    o.z = a2*nd + bz[2]; o.w = a3*nd + bz[3];
  } else {
    o.x = a4*nd + bz[0]; o.y = a5*nd + bz[1];
    o.z = a6*nd + bz[2]; o.w = a7*nd + bz[3];
  }
  *(float4*)(out + (size_t)node*OD + c0) = o;
}

extern "C" void kernel_launch(void* const* d_in, const int* in_sizes, int n_in,
                              void* d_out, int out_size, void* d_ws, size_t ws_size,
                              hipStream_t stream)
{
  const float* feat     = (const float*)d_in[0];
  const float* weight   = (const float*)d_in[1];
  const float* bias     = (const float*)d_in[2];
  const float* st_param = (const float*)d_in[3];
  const int*   src      = (const int*)d_in[4];
  const int*   dst      = (const int*)d_in[5];
  const int N = in_sizes[0] / KD;
  const int E = in_sizes[4];

  char* w = (char*)d_ws;
  size_t off = 0;
  auto take = [&](size_t bytes) -> char* {
    char* p = w + off;
    off = (off + bytes + 255) & ~(size_t)255;
    return p;
  };
  unsigned short* cnt_out = (unsigned short*)take((size_t)BCH*N*2);
  unsigned short* cnt_in  = (unsigned short*)take((size_t)BCH*N*2);
  int* cumB     = (int*)take((size_t)BCH*N*4);
  unsigned short* epos = (unsigned short*)take((size_t)E*2);
  int* indeg    = (int*)take((size_t)N*4);
  int* offsets  = (int*)take((size_t)(N+1)*4);
  int* bsum     = (int*)take(512*4);
  int* boff     = (int*)take(512*4);
  float* norm_src = (float*)take((size_t)N*4);
  unsigned short* wcT = (unsigned short*)take((size_t)KD*OD*2);
  int* esrc     = (int*)take((size_t)E*4);
  unsigned short* h2 = (unsigned short*)take((size_t)N*OD*2);
  (void)ws_size; (void)out_size; (void)n_in;

  float* out = (float*)d_out;

  // chunk size: multiple of 1024, BCH*C >= E
  int C = (((E + BCH - 1)/BCH) + 1023) & ~1023;
  int nparts = (N + RBIN - 1)/RBIN;
  dim3 gh(BCH, nparts);
  k_hist_out<<<gh, 256, 0, stream>>>(src, cnt_out, E, N, C);
  k_hist_in <<<gh, 256, 0, stream>>>(dst, cnt_in, epos, E, N, C);
  k_wc<<<(KD*OD)/256, 256, 0, stream>>>(st_param, weight, wcT);
  k_red<<<(N+255)/256, 256, 0, stream>>>(cnt_out, cnt_in, norm_src, indeg, cumB, N);
  k_gemm_mfma<<<(N+GBM-1)/GBM, 512, 0, stream>>>(feat, wcT, norm_src, h2, N);
  int nb = (N + 1023)/1024;
  k_scan1<<<nb, 256, 0, stream>>>(indeg, bsum, N);
  k_scan2<<<1, 64, 0, stream>>>(bsum, boff, nb, offsets, N);
  k_scan3<<<nb, 256, 0, stream>>>(indeg, boff, offsets, N);
  int eb4 = (E + 1023)/1024;
  k_scatter<<<eb4, 256, 0, stream>>>(src, dst, epos, offsets, cumB, esrc, E, N, C);
  k_agg<<<(N+3)/4, 256, 0, stream>>>(h2, offsets, esrc, indeg, bias, out, N);
}